// Round 3
// baseline (759.109 us; speedup 1.0000x reference)
//
#include <hip/hip_runtime.h>
#include <hip/hip_bf16.h>

#define N0   3000
#define E0   48000
#define K1N  1500
#define K2N  750
#define HID  128
#define CAP  128
#define LD2  752   // padded leading dim for A2 (16B-aligned rows)

__device__ __forceinline__ unsigned fkey(float f) {
  unsigned u = __float_as_uint(f);
  return (u & 0x80000000u) ? ~u : (u | 0x80000000u);
}

// ---------------- workspace layout (float units) ----------------
constexpr size_t F_A1    = 0;                          // K1N*K1N
constexpr size_t F_M     = F_A1 + (size_t)K1N * K1N;   // K2N*K1N  (only perm2 rows of A1^2)
constexpr size_t F_A2    = F_M + (size_t)K2N * K1N;    // K2N*LD2
constexpr size_t F_YSC   = F_A2 + (size_t)K2N * LD2;   // N0*HID
constexpr size_t F_H0    = F_YSC + (size_t)N0 * HID;   // N0*HID
constexpr size_t F_H1    = F_H0 + (size_t)N0 * HID;    // K1N*HID
constexpr size_t F_H2    = F_H1 + (size_t)K1N * HID;   // K2N*HID
constexpr size_t F_U1    = F_H2 + (size_t)K2N * HID;   // K1N*HID
constexpr size_t F_U1B   = F_U1 + (size_t)K1N * HID;   // K1N*HID
constexpr size_t F_YF    = F_U1B + (size_t)K1N * HID;  // N0*3
constexpr size_t F_SCORE = F_YF + (size_t)N0 * 3;      // N0
constexpr size_t F_GATE1 = F_SCORE + N0;               // K1N  } contiguous zero fill
constexpr size_t F_GATE2 = F_GATE1 + K1N;              // K2N  }
constexpr size_t F_DIS0  = F_GATE2 + K2N;              // N0
constexpr size_t F_DIS1  = F_DIS0 + N0;                // K1N
constexpr size_t F_DIS2  = F_DIS1 + K1N;               // K2N
constexpr size_t F_SCAL  = F_DIS2 + K2N;               // 16
constexpr size_t F_PERM1 = F_SCAL + 16;                // K1N (int) } contiguous 0 fill
constexpr size_t F_PERM2 = F_PERM1 + K1N;              // K2N (int) }
constexpr size_t F_INV1  = F_PERM2 + K2N;              // N0  (int) } contiguous -1 fill
constexpr size_t F_INV2  = F_INV1 + N0;                // K1N (int) }
constexpr size_t F_CNTI  = F_INV2 + K1N;               // N0  (int) } contiguous 0 fill
constexpr size_t F_CNTO  = F_CNTI + N0;                // N0  (int) }
constexpr size_t F_SELF  = F_CNTO + N0;                // N0  (int) }
constexpr size_t F_CI    = F_SELF + N0;                // N0*CAP (int)
constexpr size_t F_CO    = F_CI + (size_t)N0 * CAP;    // N0*CAP (int)
constexpr size_t F_END   = F_CO + (size_t)N0 * CAP;

// ---------------- utility kernels ----------------
__global__ void k_zero_f32(float* p, int n) {
  int i = blockIdx.x * blockDim.x + threadIdx.x, st = gridDim.x * blockDim.x;
  for (; i < n; i += st) p[i] = 0.0f;
}
__global__ void k_fill_i32(int* p, int n, int val) {
  int i = blockIdx.x * blockDim.x + threadIdx.x, st = gridDim.x * blockDim.x;
  for (; i < n; i += st) p[i] = val;
}

// Build per-node edge lists: col_in[d] = srcs of non-self in-edges, col_out[s] = dsts.
__global__ void k_count(const int* __restrict__ ei, int* cnt_in, int* cnt_out, int* selfc,
                        int* col_in, int* col_out) {
  int e = blockIdx.x * blockDim.x + threadIdx.x;
  if (e >= E0) return;
  int s = ei[e], d = ei[E0 + e];
  if (s == d) { atomicAdd(&selfc[d], 1); return; }
  int a = atomicAdd(&cnt_in[d], 1);
  if (a < CAP) col_in[d * CAP + a] = s;
  int b = atomicAdd(&cnt_out[s], 1);
  if (b < CAP) col_out[s * CAP + b] = d;
}

__global__ void k_dis0(const int* cnt_in, const int* selfc, float* dis0) {
  int i = blockIdx.x * blockDim.x + threadIdx.x;
  if (i < N0) dis0[i] = 1.0f / sqrtf((float)(cnt_in[i] + selfc[i] + 2));
}

// Ysc[row] = dis[row] * gate[row] * (X[src] @ W)   (block=HID threads, grid=rows)
__global__ void k_yw(const float* __restrict__ X, int Kin, int nsrc,
                     const float* __restrict__ W, const int* __restrict__ perm,
                     const float* __restrict__ gate, const float* __restrict__ dis,
                     float* __restrict__ Ysc) {
  int row = blockIdx.x, f = threadIdx.x;
  int src = row;
  if (perm) {
    src = perm[row];
    if (src < 0) src = 0;
    if (src >= nsrc) src = nsrc - 1;   // defensive clamp: never OOB
  }
  float g = gate ? gate[row] : 1.0f;
  float acc = 0.0f;
  for (int k = 0; k < Kin; ++k) acc += X[src * Kin + k] * W[k * HID + f];
  Ysc[row * HID + f] = dis[row] * g * acc;
}

// Level-0 sparse GCN aggregation: H[d] = act(dis0[d]*(sum_in Ysc[s] + (2+self)*Ysc[d]) + b)
__global__ void k_gcn_sparse(const float* __restrict__ Ysc, const int* __restrict__ cnt_in,
                             const int* __restrict__ col_in, const int* __restrict__ selfc,
                             const float* __restrict__ dis, const float* __restrict__ bias,
                             float* __restrict__ H, int act) {
  int d = blockIdx.x, f = threadIdx.x;
  int cnt = cnt_in[d]; if (cnt > CAP) cnt = CAP;
  float acc = (2.0f + (float)selfc[d]) * Ysc[d * HID + f];
  for (int e = 0; e < cnt; ++e) acc += Ysc[col_in[d * CAP + e] * HID + f];
  float z = dis[d] * acc + bias[f];
  H[d * HID + f] = act ? tanhf(z) : z;
}

__global__ void k_norm(const float* __restrict__ p, float* scal) {
  __shared__ float red[HID];
  int t = threadIdx.x;
  float v = p[t];
  red[t] = v * v; __syncthreads();
  for (int s = 64; s > 0; s >>= 1) { if (t < s) red[t] += red[t + s]; __syncthreads(); }
  if (t == 0) scal[0] = 1.0f / sqrtf(red[0]);
}

__global__ void k_score(const float* __restrict__ H, const float* __restrict__ p,
                        const float* __restrict__ scal, float* __restrict__ score) {
  __shared__ float red[HID];
  int i = blockIdx.x, t = threadIdx.x;
  red[t] = H[i * HID + t] * p[t]; __syncthreads();
  for (int s = 64; s > 0; s >>= 1) { if (t < s) red[t] += red[t + s]; __syncthreads(); }
  if (t == 0) score[i] = tanhf(red[0] * scal[0]);
}

// Single-WAVE top-K: radix-select threshold, then ordered ballot compaction.
// Ties at threshold taken in lowest-index order (matches jax.lax.top_k).
__global__ void k_topk(const float* __restrict__ score, int n, int K,
                       int* __restrict__ perm, float* __restrict__ gatec,
                       int* __restrict__ inv) {
  __shared__ int hist[256];
  __shared__ unsigned pfx_sh;
  __shared__ int rem_sh;
  int lane = threadIdx.x;   // blockDim.x == 64 (one wave)
  unsigned prefix = 0; int rem = K;
  for (int pass = 3; pass >= 0; --pass) {
    for (int i = lane; i < 256; i += 64) hist[i] = 0;
    __syncthreads();
    unsigned mhi = (pass == 3) ? 0u : (0xFFFFFFFFu << ((pass + 1) * 8));
    for (int i = lane; i < n; i += 64) {
      unsigned u = fkey(score[i]);
      if ((u & mhi) == (prefix & mhi)) atomicAdd(&hist[(u >> (pass * 8)) & 255], 1);
    }
    __syncthreads();
    if (lane == 0) {
      int cum = 0, d = 255;
      for (; d > 0; --d) { if (cum + hist[d] >= rem) break; cum += hist[d]; }
      pfx_sh = prefix | ((unsigned)d << (pass * 8));
      rem_sh = rem - cum;
    }
    __syncthreads();
    prefix = pfx_sh; rem = rem_sh;
    __syncthreads();
  }
  unsigned uthr = prefix;       // key of the K-th largest
  int c_gt = K - rem;           // count of keys strictly greater
  int base_gt = 0, base_eq = 0;
  for (int chunk = 0; chunk < n; chunk += 64) {
    int i = chunk + lane;
    bool valid = (i < n);
    float sv = valid ? score[i] : 0.0f;
    unsigned u = valid ? fkey(sv) : 0u;
    bool isgt = valid && (u > uthr);
    bool iseq = valid && (u == uthr);
    unsigned long long mg = __ballot(isgt);
    unsigned long long me = __ballot(iseq);
    unsigned long long below = (lane == 0) ? 0ull : (~0ull >> (64 - lane));
    if (isgt) {
      int pos = base_gt + (int)__popcll(mg & below);
      perm[pos] = i; gatec[pos] = sv; inv[i] = pos;
    } else if (iseq) {
      int er = base_eq + (int)__popcll(me & below);
      if (er < rem) { int pos = c_gt + er; perm[pos] = i; gatec[pos] = sv; inv[i] = pos; }
    }
    base_gt += (int)__popcll(mg);
    base_eq += (int)__popcll(me);
  }
}

// A0 augment restricted to selected nodes: A1[inv[i],inv[j]] += 1 per 2-path i<-k<-j (i!=j)
__global__ void k_pairs(const int* __restrict__ cnt_in, const int* __restrict__ col_in,
                        const int* __restrict__ cnt_out, const int* __restrict__ col_out,
                        const int* __restrict__ inv, float* __restrict__ A1) {
  __shared__ int outl[CAP], inl[CAP], invo[CAP], invi[CAP];
  int k = blockIdx.x, t = threadIdx.x;
  int no = cnt_out[k]; if (no > CAP) no = CAP;
  int ni = cnt_in[k];  if (ni > CAP) ni = CAP;
  if (t < no) { int i = col_out[k * CAP + t]; outl[t] = i; invo[t] = inv[i]; }
  if (t < ni) { int j = col_in[k * CAP + t];  inl[t] = j;  invi[t] = inv[j]; }
  __syncthreads();
  for (int a = t; a < no; a += blockDim.x) {
    int i = outl[a], ii = invo[a];
    if (ii < 0) continue;
    for (int b = 0; b < ni; ++b) {
      int jj = invi[b];
      if (jj >= 0 && i != inl[b]) atomicAdd(&A1[ii * K1N + jj], 1.0f);
    }
  }
}

// + 2*A' restricted to selected nodes
__global__ void k_edge2(const int* __restrict__ ei, const int* __restrict__ inv,
                        float* __restrict__ A1) {
  int e = blockIdx.x * blockDim.x + threadIdx.x;
  if (e >= E0) return;
  int s = ei[e], d = ei[E0 + e];
  if (s == d) return;
  int a = inv[d], b = inv[s];
  if (a >= 0 && b >= 0) atomicAdd(&A1[a * K1N + b], 2.0f);
}

__global__ void k_rowsum(const float* __restrict__ A, int n, int ld, float* __restrict__ dis) {
  __shared__ float red[256];
  int r = blockIdx.x, t = threadIdx.x;
  float acc = 0.0f;
  for (int c = t; c < n; c += 256) acc += A[(size_t)r * ld + c];
  red[t] = acc; __syncthreads();
  for (int s = 128; s > 0; s >>= 1) { if (t < s) red[t] += red[t + s]; __syncthreads(); }
  if (t == 0) dis[r] = 1.0f / sqrtf(red[0] + 2.0f);
}

// M[b] = A1[perm2[b], :] @ A1   (row-sparse AXPY; exact: integer-valued matrices)
__global__ __launch_bounds__(384) void k_sq(const float* __restrict__ A1,
                                            const int* __restrict__ perm2,
                                            float* __restrict__ M) {
  __shared__ int klist[K1N];
  __shared__ float wlist[K1N];
  __shared__ int nnz_sh;
  int blk = blockIdx.x, t = threadIdx.x;
  int i = perm2[blk];
  if (i < 0) i = 0;
  if (i >= K1N) i = K1N - 1;   // defensive clamp
  if (t == 0) nnz_sh = 0;
  __syncthreads();
  for (int c = t; c < K1N; c += 384) {
    float w = A1[(size_t)i * K1N + c];
    if (w != 0.0f) { int p = atomicAdd(&nnz_sh, 1); klist[p] = c; wlist[p] = w; }
  }
  __syncthreads();
  int nnz = nnz_sh;
  int c0 = t * 4;
  bool active = (c0 < K1N);
  float4 acc = make_float4(0.f, 0.f, 0.f, 0.f);
  for (int p = 0; p < nnz; ++p) {
    int k = klist[p]; float w = wlist[p];
    if (active) {
      const float4 v = *(const float4*)&A1[(size_t)k * K1N + c0];
      acc.x += w * v.x; acc.y += w * v.y; acc.z += w * v.z; acc.w += w * v.w;
    }
  }
  if (active) *(float4*)&M[(size_t)blk * K1N + c0] = acc;
}

// A2[a,b] = (a!=b) ? M[a, perm2[b]] + 2*A1[perm2[a], perm2[b]] : 0   (cols padded to LD2 w/ 0)
__global__ void k_a2g(const float* __restrict__ M, const float* __restrict__ A1,
                      const int* __restrict__ perm2, float* __restrict__ A2) {
  int idx = blockIdx.x * blockDim.x + threadIdx.x;
  if (idx >= K2N * LD2) return;
  int a = idx / LD2, b = idx - a * LD2;
  float v = 0.0f;
  if (b < K2N && a != b) {
    int qa = perm2[a], qb = perm2[b];
    if (qa < 0) qa = 0; if (qa >= K1N) qa = K1N - 1;
    if (qb < 0) qb = 0; if (qb >= K1N) qb = K1N - 1;
    v = M[(size_t)a * K1N + qb] + 2.0f * A1[(size_t)qa * K1N + qb];
  }
  A2[idx] = v;
}

// Dense GCN aggregation: Z[r] = act(dis[r]*(sum_b A[r,b]*Ysc[b] + 2*Ysc[r]) + bias)
// block 256 = 128 feats x 2 row-halves; 8 rows per block; float4 streaming of A rows.
__global__ void k_gcnd(const float* __restrict__ A, int n, int ld, int nb,
                       const float* __restrict__ Ysc, const float* __restrict__ dis,
                       const float* __restrict__ bias, float* __restrict__ Z, int act) {
  int t = threadIdx.x, f = t & 127, h = t >> 7;
  int r0 = blockIdx.x * 8;
  float acc[4] = {0.f, 0.f, 0.f, 0.f};
  int rr[4];
#pragma unroll
  for (int j = 0; j < 4; ++j) {
    int r = r0 + h + 2 * j;
    rr[j] = (r < n) ? r : (n - 1);
  }
  for (int b = 0; b < nb; b += 4) {
    float y0 = Ysc[(b + 0) * HID + f];
    float y1 = Ysc[(b + 1) * HID + f];
    float y2 = Ysc[(b + 2) * HID + f];
    float y3 = Ysc[(b + 3) * HID + f];
#pragma unroll
    for (int j = 0; j < 4; ++j) {
      const float4 av = *(const float4*)&A[(size_t)rr[j] * ld + b];
      acc[j] += av.x * y0 + av.y * y1 + av.z * y2 + av.w * y3;
    }
  }
#pragma unroll
  for (int j = 0; j < 4; ++j) {
    int r = r0 + h + 2 * j;
    if (r < n) {
      float z = dis[r] * (acc[j] + 2.0f * Ysc[r * HID + f]) + bias[f];
      Z[r * HID + f] = act ? tanhf(z) : z;
    }
  }
}

__global__ void k_combine(const float* __restrict__ h1, const float* __restrict__ h2,
                          const int* __restrict__ inv2, float* __restrict__ u1) {
  int idx = blockIdx.x * blockDim.x + threadIdx.x;
  if (idx >= K1N * HID) return;
  int r = idx >> 7;
  float v = h1[idx];
  int ii = inv2[r];
  if (ii >= 0 && ii < K2N) v += h2[ii * HID + (idx & 127)];
  u1[idx] = v;
}

// Yfsc[i] = dis0[i] * ((h0[i] + scatter(u1b)) @ W_up1)   [N0 x 3]
__global__ void k_yf(const float* __restrict__ h0, const float* __restrict__ u1b,
                     const int* __restrict__ inv1, const float* __restrict__ Wup1,
                     const float* __restrict__ dis0, float* __restrict__ Yfsc) {
  __shared__ float red[3][HID];
  int i = blockIdx.x, t = threadIdx.x;
  float v = h0[i * HID + t];
  int ii = inv1[i];
  if (ii >= 0 && ii < K1N) v += u1b[ii * HID + t];
#pragma unroll
  for (int c = 0; c < 3; ++c) red[c][t] = v * Wup1[t * 3 + c];
  __syncthreads();
  for (int s = 64; s > 0; s >>= 1) {
    if (t < s) { red[0][t] += red[0][t + s]; red[1][t] += red[1][t + s]; red[2][t] += red[2][t + s]; }
    __syncthreads();
  }
  if (t < 3) Yfsc[i * 3 + t] = dis0[i] * red[t][0];
}

__global__ void k_final(const float* __restrict__ Yfsc, const int* __restrict__ cnt_in,
                        const int* __restrict__ col_in, const int* __restrict__ selfc,
                        const float* __restrict__ dis0, const float* __restrict__ bup1,
                        const float* __restrict__ z, float* __restrict__ out) {
  int idx = blockIdx.x * blockDim.x + threadIdx.x;
  if (idx >= N0 * 3) return;
  int d = idx / 3, c = idx - d * 3;
  int cnt = cnt_in[d]; if (cnt > CAP) cnt = CAP;
  float acc = (2.0f + (float)selfc[d]) * Yfsc[d * 3 + c];
  for (int e = 0; e < cnt; ++e) acc += Yfsc[col_in[d * CAP + e] * 3 + c];
  out[idx] = dis0[d] * acc + bup1[c] + 0.1f * z[idx];
}

extern "C" void kernel_launch(void* const* d_in, const int* in_sizes, int n_in,
                              void* d_out, int out_size, void* d_ws, size_t ws_size,
                              hipStream_t stream) {
  const float* x   = (const float*)d_in[0];
  const float* z   = (const float*)d_in[1];
  const float* Wd0 = (const float*)d_in[2];
  const float* bd0 = (const float*)d_in[3];
  const float* Wd1 = (const float*)d_in[4];
  const float* bd1 = (const float*)d_in[5];
  const float* Wd2 = (const float*)d_in[6];
  const float* bd2 = (const float*)d_in[7];
  const float* p1  = (const float*)d_in[8];
  const float* p2  = (const float*)d_in[9];
  const float* Wu0 = (const float*)d_in[10];
  const float* bu0 = (const float*)d_in[11];
  const float* Wu1 = (const float*)d_in[12];
  const float* bu1 = (const float*)d_in[13];
  const int*   ei  = (const int*)d_in[14];

  if (ws_size < F_END * sizeof(float)) return;

  float* W     = (float*)d_ws;
  float* A1    = W + F_A1;
  float* Mm    = W + F_M;
  float* A2    = W + F_A2;
  float* Ysc   = W + F_YSC;
  float* h0    = W + F_H0;
  float* h1    = W + F_H1;
  float* h2    = W + F_H2;
  float* u1    = W + F_U1;
  float* u1b   = W + F_U1B;
  float* Yfsc  = W + F_YF;
  float* score = W + F_SCORE;
  float* gate1 = W + F_GATE1;
  float* gate2 = W + F_GATE2;
  float* dis0  = W + F_DIS0;
  float* dis1  = W + F_DIS1;
  float* dis2  = W + F_DIS2;
  float* scal  = W + F_SCAL;
  int* perm1   = (int*)(W + F_PERM1);
  int* perm2   = (int*)(W + F_PERM2);
  int* inv1    = (int*)(W + F_INV1);
  int* inv2    = (int*)(W + F_INV2);
  int* cnt_in  = (int*)(W + F_CNTI);
  int* cnt_out = (int*)(W + F_CNTO);
  int* selfc   = (int*)(W + F_SELF);
  int* col_in  = (int*)(W + F_CI);
  int* col_out = (int*)(W + F_CO);
  float* out   = (float*)d_out;

  // ---- init (ws is re-poisoned to 0xAA before every timed launch) ----
  k_zero_f32<<<1024, 256, 0, stream>>>(A1, K1N * K1N);
  k_zero_f32<<<8, 256, 0, stream>>>(gate1, K1N + K2N);           // gate1 + gate2 contiguous
  k_fill_i32<<<8, 256, 0, stream>>>(perm1, K1N + K2N, 0);        // perm1 + perm2 contiguous
  k_fill_i32<<<64, 256, 0, stream>>>(inv1, N0 + K1N, -1);        // inv1 + inv2 contiguous
  k_fill_i32<<<64, 256, 0, stream>>>(cnt_in, 3 * N0, 0);         // cnt_in/cnt_out/selfc
  k_zero_f32<<<128, 256, 0, stream>>>(out + N0 * 3, N0 * 29);    // drift_label = zeros

  // ---- edge lists + deg0 ----
  k_count<<<(E0 + 255) / 256, 256, 0, stream>>>(ei, cnt_in, cnt_out, selfc, col_in, col_out);
  k_dis0<<<(N0 + 255) / 256, 256, 0, stream>>>(cnt_in, selfc, dis0);

  // ---- level 0 GCN: h0 = tanh(gcn(A0, x, Wd0, bd0)) ----
  k_yw<<<N0, HID, 0, stream>>>(x, 32, N0, Wd0, nullptr, nullptr, dis0, Ysc);
  k_gcn_sparse<<<N0, HID, 0, stream>>>(Ysc, cnt_in, col_in, selfc, dis0, bd0, h0, 1);

  // ---- pool 1 ----
  k_norm<<<1, HID, 0, stream>>>(p1, scal);
  k_score<<<N0, HID, 0, stream>>>(h0, p1, scal, score);
  k_topk<<<1, 64, 0, stream>>>(score, N0, K1N, perm1, gate1, inv1);

  // ---- A1 = augment(A0)[perm1][:,perm1] (sparse pair enumeration) ----
  k_pairs<<<N0, 128, 0, stream>>>(cnt_in, col_in, cnt_out, col_out, inv1, A1);
  k_edge2<<<(E0 + 255) / 256, 256, 0, stream>>>(ei, inv1, A1);
  k_rowsum<<<K1N, 256, 0, stream>>>(A1, K1N, K1N, dis1);

  // ---- level 1 GCN: h1 = tanh(gcn(A1, h0[perm1]*gate1, Wd1, bd1)) ----
  k_yw<<<K1N, HID, 0, stream>>>(h0, HID, N0, Wd1, perm1, gate1, dis1, Ysc);
  k_gcnd<<<(K1N + 7) / 8, 256, 0, stream>>>(A1, K1N, K1N, K1N, Ysc, dis1, bd1, h1, 1);

  // ---- pool 2 ----
  k_norm<<<1, HID, 0, stream>>>(p2, scal);
  k_score<<<K1N, HID, 0, stream>>>(h1, p2, scal, score);
  k_topk<<<1, 64, 0, stream>>>(score, K1N, K2N, perm2, gate2, inv2);

  // ---- A2 = augment(A1)[perm2][:,perm2]: only perm2 rows of A1^2 needed ----
  k_sq<<<K2N, 384, 0, stream>>>(A1, perm2, Mm);
  k_a2g<<<(K2N * LD2 + 255) / 256, 256, 0, stream>>>(Mm, A1, perm2, A2);
  k_rowsum<<<K2N, 256, 0, stream>>>(A2, K2N, LD2, dis2);

  // ---- level 2 GCN: h2 = tanh(gcn(A2, h1[perm2]*gate2, Wd2, bd2)) ----
  k_yw<<<K2N, HID, 0, stream>>>(h1, HID, K1N, Wd2, perm2, gate2, dis2, Ysc);
  k_gcnd<<<(K2N + 7) / 8, 256, 0, stream>>>(A2, K2N, LD2, LD2, Ysc, dis2, bd2, h2, 1);

  // ---- up path ----
  k_combine<<<(K1N * HID + 255) / 256, 256, 0, stream>>>(h1, h2, inv2, u1);
  k_yw<<<K1N, HID, 0, stream>>>(u1, HID, K1N, Wu0, nullptr, nullptr, dis1, Ysc);
  k_gcnd<<<(K1N + 7) / 8, 256, 0, stream>>>(A1, K1N, K1N, K1N, Ysc, dis1, bu0, u1b, 1);

  // ---- final: drift = gcn(A0, h0 + scatter(u1b), Wu1, bu1); out = drift + 0.1*z ----
  k_yf<<<N0, HID, 0, stream>>>(h0, u1b, inv1, Wu1, dis0, Yfsc);
  k_final<<<(N0 * 3 + 255) / 256, 256, 0, stream>>>(Yfsc, cnt_in, col_in, selfc, dis0, bu1, z, out);
}

// Round 4
// 508.456 us; speedup vs baseline: 1.4930x; 1.4930x over previous
//
#include <hip/hip_runtime.h>
#include <hip/hip_bf16.h>

#define N0   3000
#define E0   48000
#define K1N  1500
#define K2N  750
#define HID  128
#define CAP  128
#define LD1  1536  // padded leading dim for A1 (= padded K for level-1 GEMMs)
#define LD2  768   // padded leading dim for A2 (= padded K for level-2 GEMM)
#define BM   32    // GEMM rows per block
#define BK   64    // GEMM K-tile
#define KS   6     // GEMM K-split chunks (deterministic partials)
#define NPR  1504  // Zp row stride (= 47*32 >= padded row count of any GEMM)
#define ATS  36    // transposed A-tile stride (BM+4, bank-spread)

__device__ __forceinline__ unsigned fkey(float f) {
  unsigned u = __float_as_uint(f);
  return (u & 0x80000000u) ? ~u : (u | 0x80000000u);
}

// ---------------- workspace layout (float units) ----------------
constexpr size_t F_A1    = 0;                          // K1N*LD1
constexpr size_t F_SCR   = F_A1 + (size_t)K1N * LD1;   // max(Mm = K2N*K1N, Zp = KS*NPR*HID)
constexpr size_t SCR_SZ  = (size_t)KS * NPR * HID;     // 1,155,072 > 1,125,000
constexpr size_t F_A2    = F_SCR + SCR_SZ;             // K2N*LD2
constexpr size_t F_YSC   = F_A2 + (size_t)K2N * LD2;   // N0*HID (>= 1536 rows)
constexpr size_t F_H0    = F_YSC + (size_t)N0 * HID;   // N0*HID
constexpr size_t F_H1    = F_H0 + (size_t)N0 * HID;    // K1N*HID
constexpr size_t F_H2    = F_H1 + (size_t)K1N * HID;   // K2N*HID
constexpr size_t F_U1    = F_H2 + (size_t)K2N * HID;   // K1N*HID
constexpr size_t F_U1B   = F_U1 + (size_t)K1N * HID;   // K1N*HID
constexpr size_t F_YF    = F_U1B + (size_t)K1N * HID;  // N0*3
constexpr size_t F_SCORE = F_YF + (size_t)N0 * 3;      // N0
constexpr size_t F_GATE1 = F_SCORE + N0;               // K1N  } contiguous zero fill
constexpr size_t F_GATE2 = F_GATE1 + K1N;              // K2N  }
constexpr size_t F_DIS0  = F_GATE2 + K2N;              // N0
constexpr size_t F_DIS1  = F_DIS0 + N0;                // K1N
constexpr size_t F_DIS2  = F_DIS1 + K1N;               // K2N
constexpr size_t F_SCAL  = F_DIS2 + K2N;               // 16
constexpr size_t F_PERM1 = F_SCAL + 16;                // K1N (int) } contiguous 0 fill
constexpr size_t F_PERM2 = F_PERM1 + K1N;              // K2N (int) }
constexpr size_t F_INV1  = F_PERM2 + K2N;              // N0  (int) } contiguous -1 fill
constexpr size_t F_INV2  = F_INV1 + N0;                // K1N (int) }
constexpr size_t F_CNTI  = F_INV2 + K1N;               // N0  (int) } contiguous 0 fill
constexpr size_t F_CNTO  = F_CNTI + N0;                // N0  (int) }
constexpr size_t F_SELF  = F_CNTO + N0;                // N0  (int) }
constexpr size_t F_CI    = F_SELF + N0;                // N0*CAP (int)
constexpr size_t F_CO    = F_CI + (size_t)N0 * CAP;    // N0*CAP (int)
constexpr size_t F_END   = F_CO + (size_t)N0 * CAP;

// ---------------- utility kernels ----------------
__global__ void k_zero_f32(float* p, int n) {
  int i = blockIdx.x * blockDim.x + threadIdx.x, st = gridDim.x * blockDim.x;
  for (; i < n; i += st) p[i] = 0.0f;
}
__global__ void k_fill_i32(int* p, int n, int val) {
  int i = blockIdx.x * blockDim.x + threadIdx.x, st = gridDim.x * blockDim.x;
  for (; i < n; i += st) p[i] = val;
}

// Build per-node edge lists: col_in[d] = srcs of non-self in-edges, col_out[s] = dsts.
__global__ void k_count(const int* __restrict__ ei, int* cnt_in, int* cnt_out, int* selfc,
                        int* col_in, int* col_out) {
  int e = blockIdx.x * blockDim.x + threadIdx.x;
  if (e >= E0) return;
  int s = ei[e], d = ei[E0 + e];
  if (s == d) { atomicAdd(&selfc[d], 1); return; }
  int a = atomicAdd(&cnt_in[d], 1);
  if (a < CAP) col_in[d * CAP + a] = s;
  int b = atomicAdd(&cnt_out[s], 1);
  if (b < CAP) col_out[s * CAP + b] = d;
}

__global__ void k_dis0(const int* cnt_in, const int* selfc, float* dis0) {
  int i = blockIdx.x * blockDim.x + threadIdx.x;
  if (i < N0) dis0[i] = 1.0f / sqrtf((float)(cnt_in[i] + selfc[i] + 2));
}

// Ysc[row] = dis[row] * gate[row] * (X[src] @ W)   (block=HID threads, grid=rows)
__global__ void k_yw(const float* __restrict__ X, int Kin, int nsrc,
                     const float* __restrict__ W, const int* __restrict__ perm,
                     const float* __restrict__ gate, const float* __restrict__ dis,
                     float* __restrict__ Ysc) {
  int row = blockIdx.x, f = threadIdx.x;
  int src = row;
  if (perm) {
    src = perm[row];
    if (src < 0) src = 0;
    if (src >= nsrc) src = nsrc - 1;   // defensive clamp: never OOB
  }
  float g = gate ? gate[row] : 1.0f;
  float acc = 0.0f;
  for (int k = 0; k < Kin; ++k) acc += X[src * Kin + k] * W[k * HID + f];
  Ysc[row * HID + f] = dis[row] * g * acc;
}

// Level-0 sparse GCN aggregation: H[d] = act(dis0[d]*(sum_in Ysc[s] + (2+self)*Ysc[d]) + b)
__global__ void k_gcn_sparse(const float* __restrict__ Ysc, const int* __restrict__ cnt_in,
                             const int* __restrict__ col_in, const int* __restrict__ selfc,
                             const float* __restrict__ dis, const float* __restrict__ bias,
                             float* __restrict__ H, int act) {
  int d = blockIdx.x, f = threadIdx.x;
  int cnt = cnt_in[d]; if (cnt > CAP) cnt = CAP;
  float acc = (2.0f + (float)selfc[d]) * Ysc[d * HID + f];
  for (int e = 0; e < cnt; ++e) acc += Ysc[col_in[d * CAP + e] * HID + f];
  float z = dis[d] * acc + bias[f];
  H[d * HID + f] = act ? tanhf(z) : z;
}

__global__ void k_norm(const float* __restrict__ p, float* scal) {
  __shared__ float red[HID];
  int t = threadIdx.x;
  float v = p[t];
  red[t] = v * v; __syncthreads();
  for (int s = 64; s > 0; s >>= 1) { if (t < s) red[t] += red[t + s]; __syncthreads(); }
  if (t == 0) scal[0] = 1.0f / sqrtf(red[0]);
}

__global__ void k_score(const float* __restrict__ H, const float* __restrict__ p,
                        const float* __restrict__ scal, float* __restrict__ score) {
  __shared__ float red[HID];
  int i = blockIdx.x, t = threadIdx.x;
  red[t] = H[i * HID + t] * p[t]; __syncthreads();
  for (int s = 64; s > 0; s >>= 1) { if (t < s) red[t] += red[t + s]; __syncthreads(); }
  if (t == 0) score[i] = tanhf(red[0] * scal[0]);
}

// Single-WAVE top-K: radix-select threshold, then ordered ballot compaction.
// Ties at threshold taken in lowest-index order (matches jax.lax.top_k).
__global__ void k_topk(const float* __restrict__ score, int n, int K,
                       int* __restrict__ perm, float* __restrict__ gatec,
                       int* __restrict__ inv) {
  __shared__ int hist[256];
  __shared__ unsigned pfx_sh;
  __shared__ int rem_sh;
  int lane = threadIdx.x;   // blockDim.x == 64 (one wave)
  unsigned prefix = 0; int rem = K;
  for (int pass = 3; pass >= 0; --pass) {
    for (int i = lane; i < 256; i += 64) hist[i] = 0;
    __syncthreads();
    unsigned mhi = (pass == 3) ? 0u : (0xFFFFFFFFu << ((pass + 1) * 8));
    for (int i = lane; i < n; i += 64) {
      unsigned u = fkey(score[i]);
      if ((u & mhi) == (prefix & mhi)) atomicAdd(&hist[(u >> (pass * 8)) & 255], 1);
    }
    __syncthreads();
    if (lane == 0) {
      int cum = 0, d = 255;
      for (; d > 0; --d) { if (cum + hist[d] >= rem) break; cum += hist[d]; }
      pfx_sh = prefix | ((unsigned)d << (pass * 8));
      rem_sh = rem - cum;
    }
    __syncthreads();
    prefix = pfx_sh; rem = rem_sh;
    __syncthreads();
  }
  unsigned uthr = prefix;       // key of the K-th largest
  int c_gt = K - rem;           // count of keys strictly greater
  int base_gt = 0, base_eq = 0;
  for (int chunk = 0; chunk < n; chunk += 64) {
    int i = chunk + lane;
    bool valid = (i < n);
    float sv = valid ? score[i] : 0.0f;
    unsigned u = valid ? fkey(sv) : 0u;
    bool isgt = valid && (u > uthr);
    bool iseq = valid && (u == uthr);
    unsigned long long mg = __ballot(isgt);
    unsigned long long me = __ballot(iseq);
    unsigned long long below = (lane == 0) ? 0ull : (~0ull >> (64 - lane));
    if (isgt) {
      int pos = base_gt + (int)__popcll(mg & below);
      perm[pos] = i; gatec[pos] = sv; inv[i] = pos;
    } else if (iseq) {
      int er = base_eq + (int)__popcll(me & below);
      if (er < rem) { int pos = c_gt + er; perm[pos] = i; gatec[pos] = sv; inv[i] = pos; }
    }
    base_gt += (int)__popcll(mg);
    base_eq += (int)__popcll(me);
  }
}

// A0 augment restricted to selected nodes: A1[inv[i],inv[j]] += 1 per 2-path i<-k<-j (i!=j)
__global__ void k_pairs(const int* __restrict__ cnt_in, const int* __restrict__ col_in,
                        const int* __restrict__ cnt_out, const int* __restrict__ col_out,
                        const int* __restrict__ inv, float* __restrict__ A1) {
  __shared__ int outl[CAP], inl[CAP], invo[CAP], invi[CAP];
  int k = blockIdx.x, t = threadIdx.x;
  int no = cnt_out[k]; if (no > CAP) no = CAP;
  int ni = cnt_in[k];  if (ni > CAP) ni = CAP;
  if (t < no) { int i = col_out[k * CAP + t]; outl[t] = i; invo[t] = inv[i]; }
  if (t < ni) { int j = col_in[k * CAP + t];  inl[t] = j;  invi[t] = inv[j]; }
  __syncthreads();
  for (int a = t; a < no; a += blockDim.x) {
    int i = outl[a], ii = invo[a];
    if (ii < 0) continue;
    for (int b = 0; b < ni; ++b) {
      int jj = invi[b];
      if (jj >= 0 && i != inl[b]) atomicAdd(&A1[(size_t)ii * LD1 + jj], 1.0f);
    }
  }
}

// + 2*A' restricted to selected nodes
__global__ void k_edge2(const int* __restrict__ ei, const int* __restrict__ inv,
                        float* __restrict__ A1) {
  int e = blockIdx.x * blockDim.x + threadIdx.x;
  if (e >= E0) return;
  int s = ei[e], d = ei[E0 + e];
  if (s == d) return;
  int a = inv[d], b = inv[s];
  if (a >= 0 && b >= 0) atomicAdd(&A1[(size_t)a * LD1 + b], 2.0f);
}

__global__ void k_rowsum(const float* __restrict__ A, int n, int ld, float* __restrict__ dis) {
  __shared__ float red[256];
  int r = blockIdx.x, t = threadIdx.x;
  float acc = 0.0f;
  for (int c = t; c < n; c += 256) acc += A[(size_t)r * ld + c];
  red[t] = acc; __syncthreads();
  for (int s = 128; s > 0; s >>= 1) { if (t < s) red[t] += red[t + s]; __syncthreads(); }
  if (t == 0) dis[r] = 1.0f / sqrtf(red[0] + 2.0f);
}

// M[b] = A1[perm2[b], :] @ A1   (row-sparse AXPY; exact: integer-valued matrices)
__global__ __launch_bounds__(384) void k_sq(const float* __restrict__ A1,
                                            const int* __restrict__ perm2,
                                            float* __restrict__ M) {
  __shared__ int klist[K1N];
  __shared__ float wlist[K1N];
  __shared__ int nnz_sh;
  int blk = blockIdx.x, t = threadIdx.x;
  int i = perm2[blk];
  if (i < 0) i = 0;
  if (i >= K1N) i = K1N - 1;   // defensive clamp
  if (t == 0) nnz_sh = 0;
  __syncthreads();
  for (int c = t; c < K1N; c += 384) {
    float w = A1[(size_t)i * LD1 + c];
    if (w != 0.0f) { int p = atomicAdd(&nnz_sh, 1); klist[p] = c; wlist[p] = w; }
  }
  __syncthreads();
  int nnz = nnz_sh;
  int c0 = t * 4;
  bool active = (c0 < K1N);
  float4 acc = make_float4(0.f, 0.f, 0.f, 0.f);
  for (int p = 0; p < nnz; ++p) {
    int k = klist[p]; float w = wlist[p];
    if (active) {
      const float4 v = *(const float4*)&A1[(size_t)k * LD1 + c0];
      acc.x += w * v.x; acc.y += w * v.y; acc.z += w * v.z; acc.w += w * v.w;
    }
  }
  if (active) *(float4*)&M[(size_t)blk * K1N + c0] = acc;
}

// A2[a,b] = (a!=b) ? M[a, perm2[b]] + 2*A1[perm2[a], perm2[b]] : 0   (cols padded to LD2 w/ 0)
__global__ void k_a2g(const float* __restrict__ M, const float* __restrict__ A1,
                      const int* __restrict__ perm2, float* __restrict__ A2) {
  int idx = blockIdx.x * blockDim.x + threadIdx.x;
  if (idx >= K2N * LD2) return;
  int a = idx / LD2, b = idx - a * LD2;
  float v = 0.0f;
  if (b < K2N && a != b) {
    int qa = perm2[a], qb = perm2[b];
    if (qa < 0) qa = 0; if (qa >= K1N) qa = K1N - 1;
    if (qb < 0) qb = 0; if (qb >= K1N) qb = K1N - 1;
    v = M[(size_t)a * K1N + qb] + 2.0f * A1[(size_t)qa * LD1 + qb];
  }
  A2[idx] = v;
}

// LDS-tiled GEMM partial: Zp[s][r][f] = sum_{k in chunk s} A[r][k] * Y[k][f]
// block: 256 thr = 32 col-groups(f4) x 8 row-groups(4 rows); BM=32 rows, BK=64 K-tile.
// ld == padded K (zero-filled), kc = chunk width (multiple of BK).
__global__ __launch_bounds__(256) void k_gemm(const float* __restrict__ A, int n, int ld,
                                              const float* __restrict__ Y,
                                              float* __restrict__ Zp, int kc) {
  __shared__ float Yt[BK * HID];   // 32 KB, [kk][f]
  __shared__ float At[BK * ATS];   // 9 KB,  [kk][row] transposed
  int t = threadIdx.x;
  int r0 = blockIdx.x * BM;
  int k0 = blockIdx.y * kc;
  int f4 = (t & 31) * 4;
  int rg = t >> 5;                 // 0..7, rows r0 + rg*4 + {0..3}
  float4 acc0 = {0,0,0,0}, acc1 = {0,0,0,0}, acc2 = {0,0,0,0}, acc3 = {0,0,0,0};
  for (int kt = 0; kt < kc; kt += BK) {
    int kb = k0 + kt;
    // stage Y tile: 8192 contiguous floats
    {
      const float4* src = (const float4*)(Y + (size_t)kb * HID);
      float4* dst = (float4*)Yt;
#pragma unroll
      for (int i = 0; i < 8; ++i) dst[i * 256 + t] = src[i * 256 + t];
    }
    // stage A tile transposed: 32 rows x 64 kk
#pragma unroll
    for (int ii = 0; ii < 2; ++ii) {
      int tix = t + ii * 256;
      int j = tix >> 4;                 // 0..31
      int kk4 = (tix & 15) * 4;         // 0..60
      int rr = r0 + j; if (rr >= n) rr = n - 1;
      float4 av = *(const float4*)(A + (size_t)rr * ld + kb + kk4);
      At[(kk4 + 0) * ATS + j] = av.x;
      At[(kk4 + 1) * ATS + j] = av.y;
      At[(kk4 + 2) * ATS + j] = av.z;
      At[(kk4 + 3) * ATS + j] = av.w;
    }
    __syncthreads();
#pragma unroll 4
    for (int kk = 0; kk < BK; ++kk) {
      float4 y = *(const float4*)&Yt[kk * HID + f4];
      float4 a = *(const float4*)&At[kk * ATS + rg * 4];
      acc0.x += a.x * y.x; acc0.y += a.x * y.y; acc0.z += a.x * y.z; acc0.w += a.x * y.w;
      acc1.x += a.y * y.x; acc1.y += a.y * y.y; acc1.z += a.y * y.z; acc1.w += a.y * y.w;
      acc2.x += a.z * y.x; acc2.y += a.z * y.y; acc2.z += a.z * y.z; acc2.w += a.z * y.w;
      acc3.x += a.w * y.x; acc3.y += a.w * y.y; acc3.z += a.w * y.z; acc3.w += a.w * y.w;
    }
    __syncthreads();
  }
  size_t zb = (size_t)blockIdx.y * NPR;
  int r = r0 + rg * 4;
  if (r + 0 < n) *(float4*)&Zp[(zb + r + 0) * HID + f4] = acc0;
  if (r + 1 < n) *(float4*)&Zp[(zb + r + 1) * HID + f4] = acc1;
  if (r + 2 < n) *(float4*)&Zp[(zb + r + 2) * HID + f4] = acc2;
  if (r + 3 < n) *(float4*)&Zp[(zb + r + 3) * HID + f4] = acc3;
}

// epilogue: Z[r][f] = act(dis[r]*(sum_s Zp[s][r][f] + 2*Ysc[r][f]) + bias[f])
__global__ void k_gcn_epi(const float* __restrict__ Zp, const float* __restrict__ Ysc,
                          const float* __restrict__ dis, const float* __restrict__ bias,
                          float* __restrict__ Z, int n, int act) {
  int idx = blockIdx.x * blockDim.x + threadIdx.x;
  if (idx >= n * HID) return;
  int r = idx >> 7, f = idx & 127;
  float acc = 0.0f;
#pragma unroll
  for (int s = 0; s < KS; ++s) acc += Zp[((size_t)s * NPR) * HID + idx];
  float z = dis[r] * (acc + 2.0f * Ysc[idx]) + bias[f];
  Z[idx] = act ? tanhf(z) : z;
}

__global__ void k_combine(const float* __restrict__ h1, const float* __restrict__ h2,
                          const int* __restrict__ inv2, float* __restrict__ u1) {
  int idx = blockIdx.x * blockDim.x + threadIdx.x;
  if (idx >= K1N * HID) return;
  int r = idx >> 7;
  float v = h1[idx];
  int ii = inv2[r];
  if (ii >= 0 && ii < K2N) v += h2[ii * HID + (idx & 127)];
  u1[idx] = v;
}

// Yfsc[i] = dis0[i] * ((h0[i] + scatter(u1b)) @ W_up1)   [N0 x 3]
__global__ void k_yf(const float* __restrict__ h0, const float* __restrict__ u1b,
                     const int* __restrict__ inv1, const float* __restrict__ Wup1,
                     const float* __restrict__ dis0, float* __restrict__ Yfsc) {
  __shared__ float red[3][HID];
  int i = blockIdx.x, t = threadIdx.x;
  float v = h0[i * HID + t];
  int ii = inv1[i];
  if (ii >= 0 && ii < K1N) v += u1b[ii * HID + t];
#pragma unroll
  for (int c = 0; c < 3; ++c) red[c][t] = v * Wup1[t * 3 + c];
  __syncthreads();
  for (int s = 64; s > 0; s >>= 1) {
    if (t < s) { red[0][t] += red[0][t + s]; red[1][t] += red[1][t + s]; red[2][t] += red[2][t + s]; }
    __syncthreads();
  }
  if (t < 3) Yfsc[i * 3 + t] = dis0[i] * red[t][0];
}

__global__ void k_final(const float* __restrict__ Yfsc, const int* __restrict__ cnt_in,
                        const int* __restrict__ col_in, const int* __restrict__ selfc,
                        const float* __restrict__ dis0, const float* __restrict__ bup1,
                        const float* __restrict__ z, float* __restrict__ out) {
  int idx = blockIdx.x * blockDim.x + threadIdx.x;
  if (idx >= N0 * 3) return;
  int d = idx / 3, c = idx - d * 3;
  int cnt = cnt_in[d]; if (cnt > CAP) cnt = CAP;
  float acc = (2.0f + (float)selfc[d]) * Yfsc[d * 3 + c];
  for (int e = 0; e < cnt; ++e) acc += Yfsc[col_in[d * CAP + e] * 3 + c];
  out[idx] = dis0[d] * acc + bup1[c] + 0.1f * z[idx];
}

extern "C" void kernel_launch(void* const* d_in, const int* in_sizes, int n_in,
                              void* d_out, int out_size, void* d_ws, size_t ws_size,
                              hipStream_t stream) {
  const float* x   = (const float*)d_in[0];
  const float* z   = (const float*)d_in[1];
  const float* Wd0 = (const float*)d_in[2];
  const float* bd0 = (const float*)d_in[3];
  const float* Wd1 = (const float*)d_in[4];
  const float* bd1 = (const float*)d_in[5];
  const float* Wd2 = (const float*)d_in[6];
  const float* bd2 = (const float*)d_in[7];
  const float* p1  = (const float*)d_in[8];
  const float* p2  = (const float*)d_in[9];
  const float* Wu0 = (const float*)d_in[10];
  const float* bu0 = (const float*)d_in[11];
  const float* Wu1 = (const float*)d_in[12];
  const float* bu1 = (const float*)d_in[13];
  const int*   ei  = (const int*)d_in[14];

  if (ws_size < F_END * sizeof(float)) return;

  float* W     = (float*)d_ws;
  float* A1    = W + F_A1;
  float* Mm    = W + F_SCR;   // aliased with Zp (disjoint live ranges)
  float* Zp    = W + F_SCR;
  float* A2    = W + F_A2;
  float* Ysc   = W + F_YSC;
  float* h0    = W + F_H0;
  float* h1    = W + F_H1;
  float* h2    = W + F_H2;
  float* u1    = W + F_U1;
  float* u1b   = W + F_U1B;
  float* Yfsc  = W + F_YF;
  float* score = W + F_SCORE;
  float* gate1 = W + F_GATE1;
  float* gate2 = W + F_GATE2;
  float* dis0  = W + F_DIS0;
  float* dis1  = W + F_DIS1;
  float* dis2  = W + F_DIS2;
  float* scal  = W + F_SCAL;
  int* perm1   = (int*)(W + F_PERM1);
  int* perm2   = (int*)(W + F_PERM2);
  int* inv1    = (int*)(W + F_INV1);
  int* inv2    = (int*)(W + F_INV2);
  int* cnt_in  = (int*)(W + F_CNTI);
  int* cnt_out = (int*)(W + F_CNTO);
  int* selfc   = (int*)(W + F_SELF);
  int* col_in  = (int*)(W + F_CI);
  int* col_out = (int*)(W + F_CO);
  float* out   = (float*)d_out;

  // ---- init (ws is re-poisoned to 0xAA before every timed launch) ----
  k_zero_f32<<<1024, 256, 0, stream>>>(A1, K1N * LD1);           // incl. K-padding cols
  k_zero_f32<<<8, 256, 0, stream>>>(gate1, K1N + K2N);           // gate1 + gate2 contiguous
  k_fill_i32<<<8, 256, 0, stream>>>(perm1, K1N + K2N, 0);        // perm1 + perm2 contiguous
  k_fill_i32<<<64, 256, 0, stream>>>(inv1, N0 + K1N, -1);        // inv1 + inv2 contiguous
  k_fill_i32<<<64, 256, 0, stream>>>(cnt_in, 3 * N0, 0);         // cnt_in/cnt_out/selfc
  k_zero_f32<<<128, 256, 0, stream>>>(out + N0 * 3, N0 * 29);    // drift_label = zeros

  // ---- edge lists + deg0 ----
  k_count<<<(E0 + 255) / 256, 256, 0, stream>>>(ei, cnt_in, cnt_out, selfc, col_in, col_out);
  k_dis0<<<(N0 + 255) / 256, 256, 0, stream>>>(cnt_in, selfc, dis0);

  // ---- level 0 GCN: h0 = tanh(gcn(A0, x, Wd0, bd0)) ----
  k_yw<<<N0, HID, 0, stream>>>(x, 32, N0, Wd0, nullptr, nullptr, dis0, Ysc);
  k_gcn_sparse<<<N0, HID, 0, stream>>>(Ysc, cnt_in, col_in, selfc, dis0, bd0, h0, 1);

  // ---- pool 1 ----
  k_norm<<<1, HID, 0, stream>>>(p1, scal);
  k_score<<<N0, HID, 0, stream>>>(h0, p1, scal, score);
  k_topk<<<1, 64, 0, stream>>>(score, N0, K1N, perm1, gate1, inv1);

  // ---- A1 = augment(A0)[perm1][:,perm1] (sparse pair enumeration) ----
  k_pairs<<<N0, 128, 0, stream>>>(cnt_in, col_in, cnt_out, col_out, inv1, A1);
  k_edge2<<<(E0 + 255) / 256, 256, 0, stream>>>(ei, inv1, A1);
  k_rowsum<<<K1N, 256, 0, stream>>>(A1, K1N, LD1, dis1);

  // ---- level 1 GCN: h1 = tanh(gcn(A1, h0[perm1]*gate1, Wd1, bd1)) ----
  k_yw<<<K1N, HID, 0, stream>>>(h0, HID, N0, Wd1, perm1, gate1, dis1, Ysc);
  k_zero_f32<<<8, 256, 0, stream>>>(Ysc + K1N * HID, (LD1 - K1N) * HID);  // K-pad rows
  k_gemm<<<dim3((K1N + BM - 1) / BM, KS), 256, 0, stream>>>(A1, K1N, LD1, Ysc, Zp, LD1 / KS);
  k_gcn_epi<<<(K1N * HID + 255) / 256, 256, 0, stream>>>(Zp, Ysc, dis1, bd1, h1, K1N, 1);

  // ---- pool 2 ----
  k_norm<<<1, HID, 0, stream>>>(p2, scal);
  k_score<<<K1N, HID, 0, stream>>>(h1, p2, scal, score);
  k_topk<<<1, 64, 0, stream>>>(score, K1N, K2N, perm2, gate2, inv2);

  // ---- A2 = augment(A1)[perm2][:,perm2]: only perm2 rows of A1^2 needed ----
  k_sq<<<K2N, 384, 0, stream>>>(A1, perm2, Mm);
  k_a2g<<<(K2N * LD2 + 255) / 256, 256, 0, stream>>>(Mm, A1, perm2, A2);
  k_rowsum<<<K2N, 256, 0, stream>>>(A2, K2N, LD2, dis2);

  // ---- level 2 GCN: h2 = tanh(gcn(A2, h1[perm2]*gate2, Wd2, bd2)) ----
  k_yw<<<K2N, HID, 0, stream>>>(h1, HID, K1N, Wd2, perm2, gate2, dis2, Ysc);
  k_zero_f32<<<8, 256, 0, stream>>>(Ysc + K2N * HID, (LD2 - K2N) * HID);  // K-pad rows
  k_gemm<<<dim3((K2N + BM - 1) / BM, KS), 256, 0, stream>>>(A2, K2N, LD2, Ysc, Zp, LD2 / KS);
  k_gcn_epi<<<(K2N * HID + 255) / 256, 256, 0, stream>>>(Zp, Ysc, dis2, bd2, h2, K2N, 1);

  // ---- up path ----
  k_combine<<<(K1N * HID + 255) / 256, 256, 0, stream>>>(h1, h2, inv2, u1);
  k_yw<<<K1N, HID, 0, stream>>>(u1, HID, K1N, Wu0, nullptr, nullptr, dis1, Ysc);
  k_zero_f32<<<8, 256, 0, stream>>>(Ysc + K1N * HID, (LD1 - K1N) * HID);  // K-pad rows
  k_gemm<<<dim3((K1N + BM - 1) / BM, KS), 256, 0, stream>>>(A1, K1N, LD1, Ysc, Zp, LD1 / KS);
  k_gcn_epi<<<(K1N * HID + 255) / 256, 256, 0, stream>>>(Zp, Ysc, dis1, bu0, u1b, K1N, 1);

  // ---- final: drift = gcn(A0, h0 + scatter(u1b), Wu1, bu1); out = drift + 0.1*z ----
  k_yf<<<N0, HID, 0, stream>>>(h0, u1b, inv1, Wu1, dis0, Yfsc);
  k_final<<<(N0 * 3 + 255) / 256, 256, 0, stream>>>(Yfsc, cnt_in, col_in, selfc, dis0, bu1, z, out);
}

// Round 5
// 426.734 us; speedup vs baseline: 1.7789x; 1.1915x over previous
//
#include <hip/hip_runtime.h>
#include <hip/hip_bf16.h>

#define N0   3000
#define E0   48000
#define K1N  1500
#define K2N  750
#define HID  128
#define CAP  128
#define LD1  1536  // padded leading dim for A1 (= padded K for level-1 GEMMs)
#define LD2  768   // padded leading dim for A2 (= padded K for level-2 GEMM)
#define BM   32    // GEMM rows per block
#define BK   64    // GEMM K-tile
#define KS   6     // GEMM K-split chunks (deterministic partials)
#define NPR  1504  // Zp row stride (= 47*32 >= padded row count of any GEMM)
#define ATS  36    // transposed A-tile stride (BM+4, bank-spread)

__device__ __forceinline__ unsigned fkey(float f) {
  unsigned u = __float_as_uint(f);
  return (u & 0x80000000u) ? ~u : (u | 0x80000000u);
}
__device__ __forceinline__ float inv_fkey(unsigned u) {
  unsigned v = (u & 0x80000000u) ? (u & 0x7FFFFFFFu) : ~u;
  return __uint_as_float(v);
}

// ---------------- workspace layout (float units) ----------------
constexpr size_t F_A1    = 0;                          // K1N*LD1
constexpr size_t F_SCR   = F_A1 + (size_t)K1N * LD1;   // max(Mm = K2N*K1N, Zp = KS*NPR*HID)
constexpr size_t SCR_SZ  = (size_t)KS * NPR * HID;     // 1,155,072 > 1,125,000
constexpr size_t F_A2    = F_SCR + SCR_SZ;             // K2N*LD2
constexpr size_t F_YSC   = F_A2 + (size_t)K2N * LD2;   // N0*HID (>= 1536 rows)
constexpr size_t F_H0    = F_YSC + (size_t)N0 * HID;   // N0*HID
constexpr size_t F_H1    = F_H0 + (size_t)N0 * HID;    // K1N*HID
constexpr size_t F_H2    = F_H1 + (size_t)K1N * HID;   // K2N*HID
constexpr size_t F_U1    = F_H2 + (size_t)K2N * HID;   // K1N*HID
constexpr size_t F_U1B   = F_U1 + (size_t)K1N * HID;   // K1N*HID
constexpr size_t F_YF    = F_U1B + (size_t)K1N * HID;  // N0*3
constexpr size_t F_SCORE = F_YF + (size_t)N0 * 3;      // N0
constexpr size_t F_GATE1 = F_SCORE + N0;               // K1N  } contiguous zero fill
constexpr size_t F_GATE2 = F_GATE1 + K1N;              // K2N  }
constexpr size_t F_DIS0  = F_GATE2 + K2N;              // N0
constexpr size_t F_DIS1  = F_DIS0 + N0;                // K1N
constexpr size_t F_DIS2  = F_DIS1 + K1N;               // K2N
constexpr size_t F_SCAL  = F_DIS2 + K2N;               // 16
constexpr size_t F_PERM1 = F_SCAL + 16;                // K1N (int) } contiguous 0 fill
constexpr size_t F_PERM2 = F_PERM1 + K1N;              // K2N (int) }
constexpr size_t F_INV1  = F_PERM2 + K2N;              // N0  (int) } contiguous -1 fill
constexpr size_t F_INV2  = F_INV1 + N0;                // K1N (int) }
constexpr size_t F_CNTI  = F_INV2 + K1N;               // N0  (int) } contiguous 0 fill
constexpr size_t F_CNTO  = F_CNTI + N0;                // N0  (int) }
constexpr size_t F_SELF  = F_CNTO + N0;                // N0  (int) }
constexpr size_t F_CI    = F_SELF + N0;                // N0*CAP (int)
constexpr size_t F_CO    = F_CI + (size_t)N0 * CAP;    // N0*CAP (int)
constexpr size_t F_END   = F_CO + (size_t)N0 * CAP;

// ---------------- utility kernels ----------------
__global__ void k_zero_f32(float* p, int n) {
  int i = blockIdx.x * blockDim.x + threadIdx.x, st = gridDim.x * blockDim.x;
  for (; i < n; i += st) p[i] = 0.0f;
}
__global__ void k_fill_i32(int* p, int n, int val) {
  int i = blockIdx.x * blockDim.x + threadIdx.x, st = gridDim.x * blockDim.x;
  for (; i < n; i += st) p[i] = val;
}

// Build per-node edge lists: col_in[d] = srcs of non-self in-edges, col_out[s] = dsts.
__global__ void k_count(const int* __restrict__ ei, int* cnt_in, int* cnt_out, int* selfc,
                        int* col_in, int* col_out) {
  int e = blockIdx.x * blockDim.x + threadIdx.x;
  if (e >= E0) return;
  int s = ei[e], d = ei[E0 + e];
  if (s == d) { atomicAdd(&selfc[d], 1); return; }
  int a = atomicAdd(&cnt_in[d], 1);
  if (a < CAP) col_in[d * CAP + a] = s;
  int b = atomicAdd(&cnt_out[s], 1);
  if (b < CAP) col_out[s * CAP + b] = d;
}

__global__ void k_dis0(const int* cnt_in, const int* selfc, float* dis0) {
  int i = blockIdx.x * blockDim.x + threadIdx.x;
  if (i < N0) dis0[i] = 1.0f / sqrtf((float)(cnt_in[i] + selfc[i] + 2));
}

// Ysc[row] = dis[row] * gate[row] * (X[src] @ W)   (block=HID threads, grid=rows)
__global__ void k_yw(const float* __restrict__ X, int Kin, int nsrc,
                     const float* __restrict__ W, const int* __restrict__ perm,
                     const float* __restrict__ gate, const float* __restrict__ dis,
                     float* __restrict__ Ysc) {
  int row = blockIdx.x, f = threadIdx.x;
  int src = row;
  if (perm) {
    src = perm[row];
    if (src < 0) src = 0;
    if (src >= nsrc) src = nsrc - 1;   // defensive clamp: never OOB
  }
  float g = gate ? gate[row] : 1.0f;
  float acc = 0.0f;
  for (int k = 0; k < Kin; ++k) acc += X[src * Kin + k] * W[k * HID + f];
  Ysc[row * HID + f] = dis[row] * g * acc;
}

// Level-0 sparse GCN aggregation: H[d] = act(dis0[d]*(sum_in Ysc[s] + (2+self)*Ysc[d]) + b)
__global__ void k_gcn_sparse(const float* __restrict__ Ysc, const int* __restrict__ cnt_in,
                             const int* __restrict__ col_in, const int* __restrict__ selfc,
                             const float* __restrict__ dis, const float* __restrict__ bias,
                             float* __restrict__ H, int act) {
  int d = blockIdx.x, f = threadIdx.x;
  int cnt = cnt_in[d]; if (cnt > CAP) cnt = CAP;
  float acc = (2.0f + (float)selfc[d]) * Ysc[d * HID + f];
  for (int e = 0; e < cnt; ++e) acc += Ysc[col_in[d * CAP + e] * HID + f];
  float z = dis[d] * acc + bias[f];
  H[d * HID + f] = act ? tanhf(z) : z;
}

__global__ void k_norm(const float* __restrict__ p, float* scal) {
  __shared__ float red[HID];
  int t = threadIdx.x;
  float v = p[t];
  red[t] = v * v; __syncthreads();
  for (int s = 64; s > 0; s >>= 1) { if (t < s) red[t] += red[t + s]; __syncthreads(); }
  if (t == 0) scal[0] = 1.0f / sqrtf(red[0]);
}

__global__ void k_score(const float* __restrict__ H, const float* __restrict__ p,
                        const float* __restrict__ scal, float* __restrict__ score) {
  __shared__ float red[HID];
  int i = blockIdx.x, t = threadIdx.x;
  red[t] = H[i * HID + t] * p[t]; __syncthreads();
  for (int s = 64; s > 0; s >>= 1) { if (t < s) red[t] += red[t + s]; __syncthreads(); }
  if (t == 0) score[i] = tanhf(red[0] * scal[0]);
}

// Top-K, one 256-thread block. Keys staged in LDS; radix-select threshold with
// parallel suffix-scan; compaction by wave 0 via verified ballot scheme.
// Ties at threshold taken in lowest-index order (matches jax.lax.top_k).
__global__ __launch_bounds__(256) void k_topk(const float* __restrict__ score, int n, int K,
                                              int* __restrict__ perm, float* __restrict__ gatec,
                                              int* __restrict__ inv) {
  __shared__ unsigned keys[N0];      // n <= N0
  __shared__ int hist[256];
  __shared__ int sscan[257];
  __shared__ unsigned pfx_sh;
  __shared__ int rem_sh;
  int t = threadIdx.x;
  // stage keys into LDS (coalesced)
  for (int i = t; i < n; i += 256) keys[i] = fkey(score[i]);
  __syncthreads();

  unsigned prefix = 0; int rem = K;
  for (int pass = 3; pass >= 0; --pass) {
    hist[t] = 0;
    __syncthreads();
    unsigned mhi = (pass == 3) ? 0u : (0xFFFFFFFFu << ((pass + 1) * 8));
    for (int i = t; i < n; i += 256) {
      unsigned u = keys[i];
      if ((u & mhi) == (prefix & mhi)) atomicAdd(&hist[(u >> (pass * 8)) & 255], 1);
    }
    __syncthreads();
    // inclusive suffix scan: sscan[d] = sum_{d'>=d} hist[d']
    sscan[t] = hist[t];
    if (t == 0) sscan[256] = 0;
    __syncthreads();
    for (int off = 1; off < 256; off <<= 1) {
      int add = (t + off < 256) ? sscan[t + off] : 0;
      __syncthreads();
      sscan[t] += add;
      __syncthreads();
    }
    // unique digit d: suffix[d] >= rem && suffix[d+1] < rem
    if (sscan[t] >= rem && sscan[t + 1] < rem) {
      pfx_sh = prefix | ((unsigned)t << (pass * 8));
      rem_sh = rem - sscan[t + 1];
    }
    __syncthreads();
    prefix = pfx_sh; rem = rem_sh;
    __syncthreads();
  }
  unsigned uthr = prefix;       // key of the K-th largest
  int c_gt = K - rem;           // count of keys strictly greater
  if (t >= 64) return;          // single-wave compaction (no further barriers)
  int lane = t;
  int base_gt = 0, base_eq = 0;
  for (int chunk = 0; chunk < n; chunk += 64) {
    int i = chunk + lane;
    bool valid = (i < n);
    unsigned u = valid ? keys[i] : 0u;
    bool isgt = valid && (u > uthr);
    bool iseq = valid && (u == uthr);
    unsigned long long mg = __ballot(isgt);
    unsigned long long me = __ballot(iseq);
    unsigned long long below = (lane == 0) ? 0ull : (~0ull >> (64 - lane));
    if (isgt) {
      int pos = base_gt + (int)__popcll(mg & below);
      perm[pos] = i; gatec[pos] = inv_fkey(u); inv[i] = pos;
    } else if (iseq) {
      int er = base_eq + (int)__popcll(me & below);
      if (er < rem) { int pos = c_gt + er; perm[pos] = i; gatec[pos] = inv_fkey(u); inv[i] = pos; }
    }
    base_gt += (int)__popcll(mg);
    base_eq += (int)__popcll(me);
  }
}

// A0 augment restricted to selected nodes: A1[inv[i],inv[j]] += 1 per 2-path i<-k<-j (i!=j)
__global__ void k_pairs(const int* __restrict__ cnt_in, const int* __restrict__ col_in,
                        const int* __restrict__ cnt_out, const int* __restrict__ col_out,
                        const int* __restrict__ inv, float* __restrict__ A1) {
  __shared__ int outl[CAP], inl[CAP], invo[CAP], invi[CAP];
  int k = blockIdx.x, t = threadIdx.x;
  int no = cnt_out[k]; if (no > CAP) no = CAP;
  int ni = cnt_in[k];  if (ni > CAP) ni = CAP;
  if (t < no) { int i = col_out[k * CAP + t]; outl[t] = i; invo[t] = inv[i]; }
  if (t < ni) { int j = col_in[k * CAP + t];  inl[t] = j;  invi[t] = inv[j]; }
  __syncthreads();
  for (int a = t; a < no; a += blockDim.x) {
    int i = outl[a], ii = invo[a];
    if (ii < 0) continue;
    for (int b = 0; b < ni; ++b) {
      int jj = invi[b];
      if (jj >= 0 && i != inl[b]) atomicAdd(&A1[(size_t)ii * LD1 + jj], 1.0f);
    }
  }
}

// + 2*A' restricted to selected nodes
__global__ void k_edge2(const int* __restrict__ ei, const int* __restrict__ inv,
                        float* __restrict__ A1) {
  int e = blockIdx.x * blockDim.x + threadIdx.x;
  if (e >= E0) return;
  int s = ei[e], d = ei[E0 + e];
  if (s == d) return;
  int a = inv[d], b = inv[s];
  if (a >= 0 && b >= 0) atomicAdd(&A1[(size_t)a * LD1 + b], 2.0f);
}

__global__ void k_rowsum(const float* __restrict__ A, int n, int ld, float* __restrict__ dis) {
  __shared__ float red[256];
  int r = blockIdx.x, t = threadIdx.x;
  float acc = 0.0f;
  for (int c = t; c < n; c += 256) acc += A[(size_t)r * ld + c];
  red[t] = acc; __syncthreads();
  for (int s = 128; s > 0; s >>= 1) { if (t < s) red[t] += red[t + s]; __syncthreads(); }
  if (t == 0) dis[r] = 1.0f / sqrtf(red[0] + 2.0f);
}

// M[b] = A1[perm2[b], :] @ A1   (row-sparse AXPY; exact: integer-valued matrices)
__global__ __launch_bounds__(384) void k_sq(const float* __restrict__ A1,
                                            const int* __restrict__ perm2,
                                            float* __restrict__ M) {
  __shared__ int klist[K1N];
  __shared__ float wlist[K1N];
  __shared__ int nnz_sh;
  int blk = blockIdx.x, t = threadIdx.x;
  int i = perm2[blk];
  if (i < 0) i = 0;
  if (i >= K1N) i = K1N - 1;   // defensive clamp
  if (t == 0) nnz_sh = 0;
  __syncthreads();
  for (int c = t; c < K1N; c += 384) {
    float w = A1[(size_t)i * LD1 + c];
    if (w != 0.0f) { int p = atomicAdd(&nnz_sh, 1); klist[p] = c; wlist[p] = w; }
  }
  __syncthreads();
  int nnz = nnz_sh;
  int c0 = t * 4;
  bool active = (c0 < K1N);
  float4 acc = make_float4(0.f, 0.f, 0.f, 0.f);
  for (int p = 0; p < nnz; ++p) {
    int k = klist[p]; float w = wlist[p];
    if (active) {
      const float4 v = *(const float4*)&A1[(size_t)k * LD1 + c0];
      acc.x += w * v.x; acc.y += w * v.y; acc.z += w * v.z; acc.w += w * v.w;
    }
  }
  if (active) *(float4*)&M[(size_t)blk * K1N + c0] = acc;
}

// A2[a,b] = (a!=b) ? M[a, perm2[b]] + 2*A1[perm2[a], perm2[b]] : 0   (cols padded to LD2 w/ 0)
__global__ void k_a2g(const float* __restrict__ M, const float* __restrict__ A1,
                      const int* __restrict__ perm2, float* __restrict__ A2) {
  int idx = blockIdx.x * blockDim.x + threadIdx.x;
  if (idx >= K2N * LD2) return;
  int a = idx / LD2, b = idx - a * LD2;
  float v = 0.0f;
  if (b < K2N && a != b) {
    int qa = perm2[a], qb = perm2[b];
    if (qa < 0) qa = 0; if (qa >= K1N) qa = K1N - 1;
    if (qb < 0) qb = 0; if (qb >= K1N) qb = K1N - 1;
    v = M[(size_t)a * K1N + qb] + 2.0f * A1[(size_t)qa * LD1 + qb];
  }
  A2[idx] = v;
}

// LDS-tiled GEMM partial: Zp[s][r][f] = sum_{k in chunk s} A[r][k] * Y[k][f]
// block: 256 thr = 32 col-groups(f4) x 8 row-groups(4 rows); BM=32 rows, BK=64 K-tile.
// ld == padded K (zero-filled), kc = chunk width (multiple of BK).
__global__ __launch_bounds__(256) void k_gemm(const float* __restrict__ A, int n, int ld,
                                              const float* __restrict__ Y,
                                              float* __restrict__ Zp, int kc) {
  __shared__ float Yt[BK * HID];   // 32 KB, [kk][f]
  __shared__ float At[BK * ATS];   // 9 KB,  [kk][row] transposed
  int t = threadIdx.x;
  int r0 = blockIdx.x * BM;
  int k0 = blockIdx.y * kc;
  int f4 = (t & 31) * 4;
  int rg = t >> 5;                 // 0..7, rows r0 + rg*4 + {0..3}
  float4 acc0 = {0,0,0,0}, acc1 = {0,0,0,0}, acc2 = {0,0,0,0}, acc3 = {0,0,0,0};
  for (int kt = 0; kt < kc; kt += BK) {
    int kb = k0 + kt;
    // stage Y tile: 8192 contiguous floats
    {
      const float4* src = (const float4*)(Y + (size_t)kb * HID);
      float4* dst = (float4*)Yt;
#pragma unroll
      for (int i = 0; i < 8; ++i) dst[i * 256 + t] = src[i * 256 + t];
    }
    // stage A tile transposed: 32 rows x 64 kk
#pragma unroll
    for (int ii = 0; ii < 2; ++ii) {
      int tix = t + ii * 256;
      int j = tix >> 4;                 // 0..31
      int kk4 = (tix & 15) * 4;         // 0..60
      int rr = r0 + j; if (rr >= n) rr = n - 1;
      float4 av = *(const float4*)(A + (size_t)rr * ld + kb + kk4);
      At[(kk4 + 0) * ATS + j] = av.x;
      At[(kk4 + 1) * ATS + j] = av.y;
      At[(kk4 + 2) * ATS + j] = av.z;
      At[(kk4 + 3) * ATS + j] = av.w;
    }
    __syncthreads();
#pragma unroll 4
    for (int kk = 0; kk < BK; ++kk) {
      float4 y = *(const float4*)&Yt[kk * HID + f4];
      float4 a = *(const float4*)&At[kk * ATS + rg * 4];
      acc0.x += a.x * y.x; acc0.y += a.x * y.y; acc0.z += a.x * y.z; acc0.w += a.x * y.w;
      acc1.x += a.y * y.x; acc1.y += a.y * y.y; acc1.z += a.y * y.z; acc1.w += a.y * y.w;
      acc2.x += a.z * y.x; acc2.y += a.z * y.y; acc2.z += a.z * y.z; acc2.w += a.z * y.w;
      acc3.x += a.w * y.x; acc3.y += a.w * y.y; acc3.z += a.w * y.z; acc3.w += a.w * y.w;
    }
    __syncthreads();
  }
  size_t zb = (size_t)blockIdx.y * NPR;
  int r = r0 + rg * 4;
  if (r + 0 < n) *(float4*)&Zp[(zb + r + 0) * HID + f4] = acc0;
  if (r + 1 < n) *(float4*)&Zp[(zb + r + 1) * HID + f4] = acc1;
  if (r + 2 < n) *(float4*)&Zp[(zb + r + 2) * HID + f4] = acc2;
  if (r + 3 < n) *(float4*)&Zp[(zb + r + 3) * HID + f4] = acc3;
}

// epilogue: Z[r][f] = act(dis[r]*(sum_s Zp[s][r][f] + 2*Ysc[r][f]) + bias[f])
__global__ void k_gcn_epi(const float* __restrict__ Zp, const float* __restrict__ Ysc,
                          const float* __restrict__ dis, const float* __restrict__ bias,
                          float* __restrict__ Z, int n, int act) {
  int idx = blockIdx.x * blockDim.x + threadIdx.x;
  if (idx >= n * HID) return;
  int r = idx >> 7, f = idx & 127;
  float acc = 0.0f;
#pragma unroll
  for (int s = 0; s < KS; ++s) acc += Zp[((size_t)s * NPR) * HID + idx];
  float z = dis[r] * (acc + 2.0f * Ysc[idx]) + bias[f];
  Z[idx] = act ? tanhf(z) : z;
}

__global__ void k_combine(const float* __restrict__ h1, const float* __restrict__ h2,
                          const int* __restrict__ inv2, float* __restrict__ u1) {
  int idx = blockIdx.x * blockDim.x + threadIdx.x;
  if (idx >= K1N * HID) return;
  int r = idx >> 7;
  float v = h1[idx];
  int ii = inv2[r];
  if (ii >= 0 && ii < K2N) v += h2[ii * HID + (idx & 127)];
  u1[idx] = v;
}

// Yfsc[i] = dis0[i] * ((h0[i] + scatter(u1b)) @ W_up1)   [N0 x 3]
__global__ void k_yf(const float* __restrict__ h0, const float* __restrict__ u1b,
                     const int* __restrict__ inv1, const float* __restrict__ Wup1,
                     const float* __restrict__ dis0, float* __restrict__ Yfsc) {
  __shared__ float red[3][HID];
  int i = blockIdx.x, t = threadIdx.x;
  float v = h0[i * HID + t];
  int ii = inv1[i];
  if (ii >= 0 && ii < K1N) v += u1b[ii * HID + t];
#pragma unroll
  for (int c = 0; c < 3; ++c) red[c][t] = v * Wup1[t * 3 + c];
  __syncthreads();
  for (int s = 64; s > 0; s >>= 1) {
    if (t < s) { red[0][t] += red[0][t + s]; red[1][t] += red[1][t + s]; red[2][t] += red[2][t + s]; }
    __syncthreads();
  }
  if (t < 3) Yfsc[i * 3 + t] = dis0[i] * red[t][0];
}

__global__ void k_final(const float* __restrict__ Yfsc, const int* __restrict__ cnt_in,
                        const int* __restrict__ col_in, const int* __restrict__ selfc,
                        const float* __restrict__ dis0, const float* __restrict__ bup1,
                        const float* __restrict__ z, float* __restrict__ out) {
  int idx = blockIdx.x * blockDim.x + threadIdx.x;
  if (idx >= N0 * 3) return;
  int d = idx / 3, c = idx - d * 3;
  int cnt = cnt_in[d]; if (cnt > CAP) cnt = CAP;
  float acc = (2.0f + (float)selfc[d]) * Yfsc[d * 3 + c];
  for (int e = 0; e < cnt; ++e) acc += Yfsc[col_in[d * CAP + e] * 3 + c];
  out[idx] = dis0[d] * acc + bup1[c] + 0.1f * z[idx];
}

extern "C" void kernel_launch(void* const* d_in, const int* in_sizes, int n_in,
                              void* d_out, int out_size, void* d_ws, size_t ws_size,
                              hipStream_t stream) {
  const float* x   = (const float*)d_in[0];
  const float* z   = (const float*)d_in[1];
  const float* Wd0 = (const float*)d_in[2];
  const float* bd0 = (const float*)d_in[3];
  const float* Wd1 = (const float*)d_in[4];
  const float* bd1 = (const float*)d_in[5];
  const float* Wd2 = (const float*)d_in[6];
  const float* bd2 = (const float*)d_in[7];
  const float* p1  = (const float*)d_in[8];
  const float* p2  = (const float*)d_in[9];
  const float* Wu0 = (const float*)d_in[10];
  const float* bu0 = (const float*)d_in[11];
  const float* Wu1 = (const float*)d_in[12];
  const float* bu1 = (const float*)d_in[13];
  const int*   ei  = (const int*)d_in[14];

  if (ws_size < F_END * sizeof(float)) return;

  float* W     = (float*)d_ws;
  float* A1    = W + F_A1;
  float* Mm    = W + F_SCR;   // aliased with Zp (disjoint live ranges)
  float* Zp    = W + F_SCR;
  float* A2    = W + F_A2;
  float* Ysc   = W + F_YSC;
  float* h0    = W + F_H0;
  float* h1    = W + F_H1;
  float* h2    = W + F_H2;
  float* u1    = W + F_U1;
  float* u1b   = W + F_U1B;
  float* Yfsc  = W + F_YF;
  float* score = W + F_SCORE;
  float* gate1 = W + F_GATE1;
  float* gate2 = W + F_GATE2;
  float* dis0  = W + F_DIS0;
  float* dis1  = W + F_DIS1;
  float* dis2  = W + F_DIS2;
  float* scal  = W + F_SCAL;
  int* perm1   = (int*)(W + F_PERM1);
  int* perm2   = (int*)(W + F_PERM2);
  int* inv1    = (int*)(W + F_INV1);
  int* inv2    = (int*)(W + F_INV2);
  int* cnt_in  = (int*)(W + F_CNTI);
  int* cnt_out = (int*)(W + F_CNTO);
  int* selfc   = (int*)(W + F_SELF);
  int* col_in  = (int*)(W + F_CI);
  int* col_out = (int*)(W + F_CO);
  float* out   = (float*)d_out;

  // ---- init (ws is re-poisoned to 0xAA before every timed launch) ----
  k_zero_f32<<<1024, 256, 0, stream>>>(A1, K1N * LD1);           // incl. K-padding cols
  k_zero_f32<<<8, 256, 0, stream>>>(gate1, K1N + K2N);           // gate1 + gate2 contiguous
  k_fill_i32<<<8, 256, 0, stream>>>(perm1, K1N + K2N, 0);        // perm1 + perm2 contiguous
  k_fill_i32<<<64, 256, 0, stream>>>(inv1, N0 + K1N, -1);        // inv1 + inv2 contiguous
  k_fill_i32<<<64, 256, 0, stream>>>(cnt_in, 3 * N0, 0);         // cnt_in/cnt_out/selfc
  k_zero_f32<<<128, 256, 0, stream>>>(out + N0 * 3, N0 * 29);    // drift_label = zeros

  // ---- edge lists + deg0 ----
  k_count<<<(E0 + 255) / 256, 256, 0, stream>>>(ei, cnt_in, cnt_out, selfc, col_in, col_out);
  k_dis0<<<(N0 + 255) / 256, 256, 0, stream>>>(cnt_in, selfc, dis0);

  // ---- level 0 GCN: h0 = tanh(gcn(A0, x, Wd0, bd0)) ----
  k_yw<<<N0, HID, 0, stream>>>(x, 32, N0, Wd0, nullptr, nullptr, dis0, Ysc);
  k_gcn_sparse<<<N0, HID, 0, stream>>>(Ysc, cnt_in, col_in, selfc, dis0, bd0, h0, 1);

  // ---- pool 1 ----
  k_norm<<<1, HID, 0, stream>>>(p1, scal);
  k_score<<<N0, HID, 0, stream>>>(h0, p1, scal, score);
  k_topk<<<1, 256, 0, stream>>>(score, N0, K1N, perm1, gate1, inv1);

  // ---- A1 = augment(A0)[perm1][:,perm1] (sparse pair enumeration) ----
  k_pairs<<<N0, 128, 0, stream>>>(cnt_in, col_in, cnt_out, col_out, inv1, A1);
  k_edge2<<<(E0 + 255) / 256, 256, 0, stream>>>(ei, inv1, A1);
  k_rowsum<<<K1N, 256, 0, stream>>>(A1, K1N, LD1, dis1);

  // ---- level 1 GCN: h1 = tanh(gcn(A1, h0[perm1]*gate1, Wd1, bd1)) ----
  k_yw<<<K1N, HID, 0, stream>>>(h0, HID, N0, Wd1, perm1, gate1, dis1, Ysc);
  k_zero_f32<<<8, 256, 0, stream>>>(Ysc + K1N * HID, (LD1 - K1N) * HID);  // K-pad rows
  k_gemm<<<dim3((K1N + BM - 1) / BM, KS), 256, 0, stream>>>(A1, K1N, LD1, Ysc, Zp, LD1 / KS);
  k_gcn_epi<<<(K1N * HID + 255) / 256, 256, 0, stream>>>(Zp, Ysc, dis1, bd1, h1, K1N, 1);

  // ---- pool 2 ----
  k_norm<<<1, HID, 0, stream>>>(p2, scal);
  k_score<<<K1N, HID, 0, stream>>>(h1, p2, scal, score);
  k_topk<<<1, 256, 0, stream>>>(score, K1N, K2N, perm2, gate2, inv2);

  // ---- A2 = augment(A1)[perm2][:,perm2]: only perm2 rows of A1^2 needed ----
  k_sq<<<K2N, 384, 0, stream>>>(A1, perm2, Mm);
  k_a2g<<<(K2N * LD2 + 255) / 256, 256, 0, stream>>>(Mm, A1, perm2, A2);
  k_rowsum<<<K2N, 256, 0, stream>>>(A2, K2N, LD2, dis2);

  // ---- level 2 GCN: h2 = tanh(gcn(A2, h1[perm2]*gate2, Wd2, bd2)) ----
  k_yw<<<K2N, HID, 0, stream>>>(h1, HID, K1N, Wd2, perm2, gate2, dis2, Ysc);
  k_zero_f32<<<8, 256, 0, stream>>>(Ysc + K2N * HID, (LD2 - K2N) * HID);  // K-pad rows
  k_gemm<<<dim3((K2N + BM - 1) / BM, KS), 256, 0, stream>>>(A2, K2N, LD2, Ysc, Zp, LD2 / KS);
  k_gcn_epi<<<(K2N * HID + 255) / 256, 256, 0, stream>>>(Zp, Ysc, dis2, bd2, h2, K2N, 1);

  // ---- up path ----
  k_combine<<<(K1N * HID + 255) / 256, 256, 0, stream>>>(h1, h2, inv2, u1);
  k_yw<<<K1N, HID, 0, stream>>>(u1, HID, K1N, Wu0, nullptr, nullptr, dis1, Ysc);
  k_zero_f32<<<8, 256, 0, stream>>>(Ysc + K1N * HID, (LD1 - K1N) * HID);  // K-pad rows
  k_gemm<<<dim3((K1N + BM - 1) / BM, KS), 256, 0, stream>>>(A1, K1N, LD1, Ysc, Zp, LD1 / KS);
  k_gcn_epi<<<(K1N * HID + 255) / 256, 256, 0, stream>>>(Zp, Ysc, dis1, bu0, u1b, K1N, 1);

  // ---- final: drift = gcn(A0, h0 + scatter(u1b), Wu1, bu1); out = drift + 0.1*z ----
  k_yf<<<N0, HID, 0, stream>>>(h0, u1b, inv1, Wu1, dis0, Yfsc);
  k_final<<<(N0 * 3 + 255) / 256, 256, 0, stream>>>(Yfsc, cnt_in, col_in, selfc, dis0, bu1, z, out);
}

// Round 6
// 385.126 us; speedup vs baseline: 1.9711x; 1.1080x over previous
//
#include <hip/hip_runtime.h>
#include <hip/hip_bf16.h>

#define N0   3000
#define E0   48000
#define K1N  1500
#define K2N  750
#define HID  128
#define CAP  128
#define LD1  1536  // padded leading dim for A1 (= padded K for level-1 GEMMs)
#define LD2  768   // padded leading dim for A2/Ac (= padded K for level-2 GEMM)
#define BM   32    // GEMM rows per block
#define BK   64    // GEMM K-tile
#define KS   6     // GEMM K-split chunks (deterministic partials)
#define NPR  1504  // Zp row stride (= 47*32 >= padded row count of any GEMM)
#define ATS  36    // transposed A-tile stride (BM+4, bank-spread)

__device__ __forceinline__ unsigned fkey(float f) {
  unsigned u = __float_as_uint(f);
  return (u & 0x80000000u) ? ~u : (u | 0x80000000u);
}
__device__ __forceinline__ float inv_fkey(unsigned u) {
  unsigned v = (u & 0x80000000u) ? (u & 0x7FFFFFFFu) : ~u;
  return __uint_as_float(v);
}

// ---------------- workspace layout (float units) ----------------
constexpr size_t F_A1    = 0;                          // K1N*LD1
constexpr size_t F_SCR   = F_A1 + (size_t)K1N * LD1;   // max(Zp = KS*NPR*HID, Ac = K1N*LD2)
constexpr size_t SCR_SZ  = (size_t)KS * NPR * HID;     // 1,155,072 > 1,152,000
constexpr size_t F_A2    = F_SCR + SCR_SZ;             // K2N*LD2
constexpr size_t F_YSC   = F_A2 + (size_t)K2N * LD2;   // N0*HID (>= 1536 rows)
constexpr size_t F_H0    = F_YSC + (size_t)N0 * HID;   // N0*HID
constexpr size_t F_H1    = F_H0 + (size_t)N0 * HID;    // K1N*HID
constexpr size_t F_H2    = F_H1 + (size_t)K1N * HID;   // K2N*HID
constexpr size_t F_U1    = F_H2 + (size_t)K2N * HID;   // K1N*HID
constexpr size_t F_U1B   = F_U1 + (size_t)K1N * HID;   // K1N*HID
constexpr size_t F_YF    = F_U1B + (size_t)K1N * HID;  // N0*3
constexpr size_t F_SCORE = F_YF + (size_t)N0 * 3;      // N0
constexpr size_t F_GATE1 = F_SCORE + N0;               // K1N  } contiguous zero fill
constexpr size_t F_GATE2 = F_GATE1 + K1N;              // K2N  }
constexpr size_t F_DIS0  = F_GATE2 + K2N;              // N0
constexpr size_t F_DIS1  = F_DIS0 + N0;                // K1N
constexpr size_t F_DIS2  = F_DIS1 + K1N;               // K2N
constexpr size_t F_PERM1 = F_DIS2 + K2N;               // K1N (int) } contiguous 0 fill
constexpr size_t F_PERM2 = F_PERM1 + K1N;              // K2N (int) }
constexpr size_t F_INV1  = F_PERM2 + K2N;              // N0  (int) } contiguous -1 fill
constexpr size_t F_INV2  = F_INV1 + N0;                // K1N (int) }
constexpr size_t F_CNTI  = F_INV2 + K1N;               // N0  (int) } contiguous 0 fill
constexpr size_t F_CNTO  = F_CNTI + N0;                // N0  (int) }
constexpr size_t F_SELF  = F_CNTO + N0;                // N0  (int) }
constexpr size_t F_CI    = F_SELF + N0;                // N0*CAP (int)
constexpr size_t F_CO    = F_CI + (size_t)N0 * CAP;    // N0*CAP (int)
constexpr size_t F_END   = F_CO + (size_t)N0 * CAP;

// ---------------- init: all fills fused (1 dispatch) ----------------
__global__ void k_init(float* __restrict__ A1, float* __restrict__ gate,
                       int* __restrict__ perm, int* __restrict__ inv,
                       int* __restrict__ cnt, float* __restrict__ outlab) {
  int i = blockIdx.x * blockDim.x + threadIdx.x, st = gridDim.x * blockDim.x;
  for (int j = i; j < K1N * LD1; j += st) A1[j] = 0.0f;
  for (int j = i; j < K1N + K2N; j += st) gate[j] = 0.0f;
  for (int j = i; j < K1N + K2N; j += st) perm[j] = 0;
  for (int j = i; j < N0 + K1N; j += st) inv[j] = -1;
  for (int j = i; j < 3 * N0; j += st) cnt[j] = 0;
  for (int j = i; j < N0 * 29; j += st) outlab[j] = 0.0f;
}

__global__ void k_zero_f32(float* p, int n) {
  int i = blockIdx.x * blockDim.x + threadIdx.x, st = gridDim.x * blockDim.x;
  for (; i < n; i += st) p[i] = 0.0f;
}

// Build per-node edge lists: col_in[d] = srcs of non-self in-edges, col_out[s] = dsts.
__global__ void k_count(const int* __restrict__ ei, int* cnt_in, int* cnt_out, int* selfc,
                        int* col_in, int* col_out) {
  int e = blockIdx.x * blockDim.x + threadIdx.x;
  if (e >= E0) return;
  int s = ei[e], d = ei[E0 + e];
  if (s == d) { atomicAdd(&selfc[d], 1); return; }
  int a = atomicAdd(&cnt_in[d], 1);
  if (a < CAP) col_in[d * CAP + a] = s;
  int b = atomicAdd(&cnt_out[s], 1);
  if (b < CAP) col_out[s * CAP + b] = d;
}

__global__ void k_dis0(const int* cnt_in, const int* selfc, float* dis0) {
  int i = blockIdx.x * blockDim.x + threadIdx.x;
  if (i < N0) dis0[i] = 1.0f / sqrtf((float)(cnt_in[i] + selfc[i] + 2));
}

// Ysc[row] = dis[row] * gate[row] * (X[src] @ W)   (block=HID threads, grid=rows)
__global__ void k_yw(const float* __restrict__ X, int Kin, int nsrc,
                     const float* __restrict__ W, const int* __restrict__ perm,
                     const float* __restrict__ gate, const float* __restrict__ dis,
                     float* __restrict__ Ysc) {
  int row = blockIdx.x, f = threadIdx.x;
  int src = row;
  if (perm) {
    src = perm[row];
    if (src < 0) src = 0;
    if (src >= nsrc) src = nsrc - 1;   // defensive clamp: never OOB
  }
  float g = gate ? gate[row] : 1.0f;
  float acc = 0.0f;
  for (int k = 0; k < Kin; ++k) acc += X[src * Kin + k] * W[k * HID + f];
  Ysc[row * HID + f] = dis[row] * g * acc;
}

// Level-0 sparse GCN aggregation: H[d] = act(dis0[d]*(sum_in Ysc[s] + (2+self)*Ysc[d]) + b)
__global__ void k_gcn_sparse(const float* __restrict__ Ysc, const int* __restrict__ cnt_in,
                             const int* __restrict__ col_in, const int* __restrict__ selfc,
                             const float* __restrict__ dis, const float* __restrict__ bias,
                             float* __restrict__ H, int act) {
  int d = blockIdx.x, f = threadIdx.x;
  int cnt = cnt_in[d]; if (cnt > CAP) cnt = CAP;
  float acc = (2.0f + (float)selfc[d]) * Ysc[d * HID + f];
  for (int e = 0; e < cnt; ++e) acc += Ysc[col_in[d * CAP + e] * HID + f];
  float z = dis[d] * acc + bias[f];
  H[d * HID + f] = act ? tanhf(z) : z;
}

// score[i] = tanh((H[i].p) / ||p||)   (p-norm recomputed per block, same order as before)
__global__ void k_score(const float* __restrict__ H, const float* __restrict__ p,
                        float* __restrict__ score) {
  __shared__ float red[HID];
  __shared__ float red2[HID];
  int i = blockIdx.x, t = threadIdx.x;
  float pv = p[t];
  red[t] = H[i * HID + t] * pv;
  red2[t] = pv * pv;
  __syncthreads();
  for (int s = 64; s > 0; s >>= 1) {
    if (t < s) { red[t] += red[t + s]; red2[t] += red2[t + s]; }
    __syncthreads();
  }
  if (t == 0) score[i] = tanhf(red[0] * (1.0f / sqrtf(red2[0])));
}

// Top-K, one 256-thread block. Keys staged in LDS; radix-select threshold with
// parallel suffix-scan; compaction by wave 0 via verified ballot scheme.
// Ties at threshold taken in lowest-index order (matches jax.lax.top_k).
__global__ __launch_bounds__(256) void k_topk(const float* __restrict__ score, int n, int K,
                                              int* __restrict__ perm, float* __restrict__ gatec,
                                              int* __restrict__ inv) {
  __shared__ unsigned keys[N0];      // n <= N0
  __shared__ int hist[256];
  __shared__ int sscan[257];
  __shared__ unsigned pfx_sh;
  __shared__ int rem_sh;
  int t = threadIdx.x;
  for (int i = t; i < n; i += 256) keys[i] = fkey(score[i]);
  __syncthreads();

  unsigned prefix = 0; int rem = K;
  for (int pass = 3; pass >= 0; --pass) {
    hist[t] = 0;
    __syncthreads();
    unsigned mhi = (pass == 3) ? 0u : (0xFFFFFFFFu << ((pass + 1) * 8));
    for (int i = t; i < n; i += 256) {
      unsigned u = keys[i];
      if ((u & mhi) == (prefix & mhi)) atomicAdd(&hist[(u >> (pass * 8)) & 255], 1);
    }
    __syncthreads();
    sscan[t] = hist[t];
    if (t == 0) sscan[256] = 0;
    __syncthreads();
    for (int off = 1; off < 256; off <<= 1) {
      int add = (t + off < 256) ? sscan[t + off] : 0;
      __syncthreads();
      sscan[t] += add;
      __syncthreads();
    }
    if (sscan[t] >= rem && sscan[t + 1] < rem) {
      pfx_sh = prefix | ((unsigned)t << (pass * 8));
      rem_sh = rem - sscan[t + 1];
    }
    __syncthreads();
    prefix = pfx_sh; rem = rem_sh;
    __syncthreads();
  }
  unsigned uthr = prefix;       // key of the K-th largest
  int c_gt = K - rem;           // count of keys strictly greater
  if (t >= 64) return;          // single-wave compaction (no further barriers)
  int lane = t;
  int base_gt = 0, base_eq = 0;
  for (int chunk = 0; chunk < n; chunk += 64) {
    int i = chunk + lane;
    bool valid = (i < n);
    unsigned u = valid ? keys[i] : 0u;
    bool isgt = valid && (u > uthr);
    bool iseq = valid && (u == uthr);
    unsigned long long mg = __ballot(isgt);
    unsigned long long me = __ballot(iseq);
    unsigned long long below = (lane == 0) ? 0ull : (~0ull >> (64 - lane));
    if (isgt) {
      int pos = base_gt + (int)__popcll(mg & below);
      perm[pos] = i; gatec[pos] = inv_fkey(u); inv[i] = pos;
    } else if (iseq) {
      int er = base_eq + (int)__popcll(me & below);
      if (er < rem) { int pos = c_gt + er; perm[pos] = i; gatec[pos] = inv_fkey(u); inv[i] = pos; }
    }
    base_gt += (int)__popcll(mg);
    base_eq += (int)__popcll(me);
  }
}

// A0 augment restricted to selected nodes: A1[inv[i],inv[j]] += 1 per 2-path i<-k<-j (i!=j)
__global__ void k_pairs(const int* __restrict__ cnt_in, const int* __restrict__ col_in,
                        const int* __restrict__ cnt_out, const int* __restrict__ col_out,
                        const int* __restrict__ inv, float* __restrict__ A1) {
  __shared__ int outl[CAP], inl[CAP], invo[CAP], invi[CAP];
  int k = blockIdx.x, t = threadIdx.x;
  int no = cnt_out[k]; if (no > CAP) no = CAP;
  int ni = cnt_in[k];  if (ni > CAP) ni = CAP;
  if (t < no) { int i = col_out[k * CAP + t]; outl[t] = i; invo[t] = inv[i]; }
  if (t < ni) { int j = col_in[k * CAP + t];  inl[t] = j;  invi[t] = inv[j]; }
  __syncthreads();
  for (int a = t; a < no; a += blockDim.x) {
    int i = outl[a], ii = invo[a];
    if (ii < 0) continue;
    for (int b = 0; b < ni; ++b) {
      int jj = invi[b];
      if (jj >= 0 && i != inl[b]) atomicAdd(&A1[(size_t)ii * LD1 + jj], 1.0f);
    }
  }
}

// + 2*A' restricted to selected nodes
__global__ void k_edge2(const int* __restrict__ ei, const int* __restrict__ inv,
                        float* __restrict__ A1) {
  int e = blockIdx.x * blockDim.x + threadIdx.x;
  if (e >= E0) return;
  int s = ei[e], d = ei[E0 + e];
  if (s == d) return;
  int a = inv[d], b = inv[s];
  if (a >= 0 && b >= 0) atomicAdd(&A1[(size_t)a * LD1 + b], 2.0f);
}

__global__ void k_rowsum(const float* __restrict__ A, int n, int ld, float* __restrict__ dis) {
  __shared__ float red[256];
  int r = blockIdx.x, t = threadIdx.x;
  float acc = 0.0f;
  for (int c = t; c < n; c += 256) acc += A[(size_t)r * ld + c];
  red[t] = acc; __syncthreads();
  for (int s = 128; s > 0; s >>= 1) { if (t < s) red[t] += red[t + s]; __syncthreads(); }
  if (t == 0) dis[r] = 1.0f / sqrtf(red[0] + 2.0f);
}

// Column compaction: Ac[k][b] = A1[k][perm2[b]]  (b < K2N, else 0); grid = K1N rows
__global__ __launch_bounds__(256) void k_cmp(const float* __restrict__ A1,
                                             const int* __restrict__ perm2,
                                             float* __restrict__ Ac) {
  __shared__ int q[K2N];
  int k = blockIdx.x, t = threadIdx.x;
  for (int i = t; i < K2N; i += 256) {
    int v = perm2[i];
    if (v < 0) v = 0;
    if (v >= K1N) v = K1N - 1;
    q[i] = v;
  }
  __syncthreads();
  const float* row = A1 + (size_t)k * LD1;
  float* dst = Ac + (size_t)k * LD2;
  for (int b = t; b < LD2; b += 256) dst[b] = (b < K2N) ? row[q[b]] : 0.0f;
}

// A2[a][b] = (b!=a) ? sum_k A1[qa][k]*Ac[k][b] + 2*A1[qa][perm2[b]] : 0
// Row-sparse AXPY over compacted columns; integer-exact fp32. Grid = K2N rows.
__global__ __launch_bounds__(256) void k_sq2(const float* __restrict__ A1,
                                             const float* __restrict__ Ac,
                                             const int* __restrict__ perm2,
                                             float* __restrict__ A2) {
  __shared__ int klist[K1N];
  __shared__ float wlist[K1N];
  __shared__ int nnz_sh;
  int a = blockIdx.x, t = threadIdx.x;
  int qa = perm2[a];
  if (qa < 0) qa = 0;
  if (qa >= K1N) qa = K1N - 1;
  if (t == 0) nnz_sh = 0;
  __syncthreads();
  const float* arow = A1 + (size_t)qa * LD1;
  for (int c = t; c < K1N; c += 256) {
    float w = arow[c];
    if (w != 0.0f) { int p = atomicAdd(&nnz_sh, 1); klist[p] = c; wlist[p] = w; }
  }
  __syncthreads();
  int nnz = nnz_sh;
  int c0 = t * 4;
  bool active = (c0 < LD2);
  float4 acc = make_float4(0.f, 0.f, 0.f, 0.f);
  int p = 0;
  for (; p + 4 <= nnz; p += 4) {   // 4 independent L2 loads in flight
    int k0 = klist[p], k1 = klist[p + 1], k2 = klist[p + 2], k3 = klist[p + 3];
    float w0 = wlist[p], w1 = wlist[p + 1], w2 = wlist[p + 2], w3 = wlist[p + 3];
    if (active) {
      float4 v0 = *(const float4*)&Ac[(size_t)k0 * LD2 + c0];
      float4 v1 = *(const float4*)&Ac[(size_t)k1 * LD2 + c0];
      float4 v2 = *(const float4*)&Ac[(size_t)k2 * LD2 + c0];
      float4 v3 = *(const float4*)&Ac[(size_t)k3 * LD2 + c0];
      acc.x += w0 * v0.x; acc.y += w0 * v0.y; acc.z += w0 * v0.z; acc.w += w0 * v0.w;
      acc.x += w1 * v1.x; acc.y += w1 * v1.y; acc.z += w1 * v1.z; acc.w += w1 * v1.w;
      acc.x += w2 * v2.x; acc.y += w2 * v2.y; acc.z += w2 * v2.z; acc.w += w2 * v2.w;
      acc.x += w3 * v3.x; acc.y += w3 * v3.y; acc.z += w3 * v3.z; acc.w += w3 * v3.w;
    }
  }
  for (; p < nnz; ++p) {
    int k = klist[p]; float w = wlist[p];
    if (active) {
      float4 v = *(const float4*)&Ac[(size_t)k * LD2 + c0];
      acc.x += w * v.x; acc.y += w * v.y; acc.z += w * v.z; acc.w += w * v.w;
    }
  }
  if (active) {
    float accv[4] = {acc.x, acc.y, acc.z, acc.w};
    float outv[4];
#pragma unroll
    for (int j = 0; j < 4; ++j) {
      int col = c0 + j;
      float v = 0.0f;
      if (col < K2N && col != a) {
        int qb = perm2[col];
        if (qb < 0) qb = 0;
        if (qb >= K1N) qb = K1N - 1;
        v = accv[j] + 2.0f * arow[qb];
      }
      outv[j] = v;
    }
    *(float4*)&A2[(size_t)a * LD2 + c0] = make_float4(outv[0], outv[1], outv[2], outv[3]);
  }
}

// LDS-tiled GEMM partial: Zp[s][r][f] = sum_{k in chunk s} A[r][k] * Y[k][f]
// block: 256 thr = 32 col-groups(f4) x 8 row-groups(4 rows); BM=32 rows, BK=64 K-tile.
// ld == padded K (zero-filled), kc = chunk width (multiple of BK).
__global__ __launch_bounds__(256) void k_gemm(const float* __restrict__ A, int n, int ld,
                                              const float* __restrict__ Y,
                                              float* __restrict__ Zp, int kc) {
  __shared__ float Yt[BK * HID];   // 32 KB, [kk][f]
  __shared__ float At[BK * ATS];   // 9 KB,  [kk][row] transposed
  int t = threadIdx.x;
  int r0 = blockIdx.x * BM;
  int k0 = blockIdx.y * kc;
  int f4 = (t & 31) * 4;
  int rg = t >> 5;                 // 0..7, rows r0 + rg*4 + {0..3}
  float4 acc0 = {0,0,0,0}, acc1 = {0,0,0,0}, acc2 = {0,0,0,0}, acc3 = {0,0,0,0};
  for (int kt = 0; kt < kc; kt += BK) {
    int kb = k0 + kt;
    {
      const float4* src = (const float4*)(Y + (size_t)kb * HID);
      float4* dst = (float4*)Yt;
#pragma unroll
      for (int i = 0; i < 8; ++i) dst[i * 256 + t] = src[i * 256 + t];
    }
#pragma unroll
    for (int ii = 0; ii < 2; ++ii) {
      int tix = t + ii * 256;
      int j = tix >> 4;                 // 0..31
      int kk4 = (tix & 15) * 4;         // 0..60
      int rr = r0 + j; if (rr >= n) rr = n - 1;
      float4 av = *(const float4*)(A + (size_t)rr * ld + kb + kk4);
      At[(kk4 + 0) * ATS + j] = av.x;
      At[(kk4 + 1) * ATS + j] = av.y;
      At[(kk4 + 2) * ATS + j] = av.z;
      At[(kk4 + 3) * ATS + j] = av.w;
    }
    __syncthreads();
#pragma unroll 4
    for (int kk = 0; kk < BK; ++kk) {
      float4 y = *(const float4*)&Yt[kk * HID + f4];
      float4 a = *(const float4*)&At[kk * ATS + rg * 4];
      acc0.x += a.x * y.x; acc0.y += a.x * y.y; acc0.z += a.x * y.z; acc0.w += a.x * y.w;
      acc1.x += a.y * y.x; acc1.y += a.y * y.y; acc1.z += a.y * y.z; acc1.w += a.y * y.w;
      acc2.x += a.z * y.x; acc2.y += a.z * y.y; acc2.z += a.z * y.z; acc2.w += a.z * y.w;
      acc3.x += a.w * y.x; acc3.y += a.w * y.y; acc3.z += a.w * y.z; acc3.w += a.w * y.w;
    }
    __syncthreads();
  }
  size_t zb = (size_t)blockIdx.y * NPR;
  int r = r0 + rg * 4;
  if (r + 0 < n) *(float4*)&Zp[(zb + r + 0) * HID + f4] = acc0;
  if (r + 1 < n) *(float4*)&Zp[(zb + r + 1) * HID + f4] = acc1;
  if (r + 2 < n) *(float4*)&Zp[(zb + r + 2) * HID + f4] = acc2;
  if (r + 3 < n) *(float4*)&Zp[(zb + r + 3) * HID + f4] = acc3;
}

// epilogue: Z[r][f] = act(dis[r]*(sum_s Zp[s][r][f] + 2*Ysc[r][f]) + bias[f])
__global__ void k_gcn_epi(const float* __restrict__ Zp, const float* __restrict__ Ysc,
                          const float* __restrict__ dis, const float* __restrict__ bias,
                          float* __restrict__ Z, int n, int act) {
  int idx = blockIdx.x * blockDim.x + threadIdx.x;
  if (idx >= n * HID) return;
  int r = idx >> 7, f = idx & 127;
  float acc = 0.0f;
#pragma unroll
  for (int s = 0; s < KS; ++s) acc += Zp[((size_t)s * NPR) * HID + idx];
  float z = dis[r] * (acc + 2.0f * Ysc[idx]) + bias[f];
  Z[idx] = act ? tanhf(z) : z;
}

__global__ void k_combine(const float* __restrict__ h1, const float* __restrict__ h2,
                          const int* __restrict__ inv2, float* __restrict__ u1) {
  int idx = blockIdx.x * blockDim.x + threadIdx.x;
  if (idx >= K1N * HID) return;
  int r = idx >> 7;
  float v = h1[idx];
  int ii = inv2[r];
  if (ii >= 0 && ii < K2N) v += h2[ii * HID + (idx & 127)];
  u1[idx] = v;
}

// Yfsc[i] = dis0[i] * ((h0[i] + scatter(u1b)) @ W_up1)   [N0 x 3]
__global__ void k_yf(const float* __restrict__ h0, const float* __restrict__ u1b,
                     const int* __restrict__ inv1, const float* __restrict__ Wup1,
                     const float* __restrict__ dis0, float* __restrict__ Yfsc) {
  __shared__ float red[3][HID];
  int i = blockIdx.x, t = threadIdx.x;
  float v = h0[i * HID + t];
  int ii = inv1[i];
  if (ii >= 0 && ii < K1N) v += u1b[ii * HID + t];
#pragma unroll
  for (int c = 0; c < 3; ++c) red[c][t] = v * Wup1[t * 3 + c];
  __syncthreads();
  for (int s = 64; s > 0; s >>= 1) {
    if (t < s) { red[0][t] += red[0][t + s]; red[1][t] += red[1][t + s]; red[2][t] += red[2][t + s]; }
    __syncthreads();
  }
  if (t < 3) Yfsc[i * 3 + t] = dis0[i] * red[t][0];
}

__global__ void k_final(const float* __restrict__ Yfsc, const int* __restrict__ cnt_in,
                        const int* __restrict__ col_in, const int* __restrict__ selfc,
                        const float* __restrict__ dis0, const float* __restrict__ bup1,
                        const float* __restrict__ z, float* __restrict__ out) {
  int idx = blockIdx.x * blockDim.x + threadIdx.x;
  if (idx >= N0 * 3) return;
  int d = idx / 3, c = idx - d * 3;
  int cnt = cnt_in[d]; if (cnt > CAP) cnt = CAP;
  float acc = (2.0f + (float)selfc[d]) * Yfsc[d * 3 + c];
  for (int e = 0; e < cnt; ++e) acc += Yfsc[col_in[d * CAP + e] * 3 + c];
  out[idx] = dis0[d] * acc + bup1[c] + 0.1f * z[idx];
}

extern "C" void kernel_launch(void* const* d_in, const int* in_sizes, int n_in,
                              void* d_out, int out_size, void* d_ws, size_t ws_size,
                              hipStream_t stream) {
  const float* x   = (const float*)d_in[0];
  const float* z   = (const float*)d_in[1];
  const float* Wd0 = (const float*)d_in[2];
  const float* bd0 = (const float*)d_in[3];
  const float* Wd1 = (const float*)d_in[4];
  const float* bd1 = (const float*)d_in[5];
  const float* Wd2 = (const float*)d_in[6];
  const float* bd2 = (const float*)d_in[7];
  const float* p1  = (const float*)d_in[8];
  const float* p2  = (const float*)d_in[9];
  const float* Wu0 = (const float*)d_in[10];
  const float* bu0 = (const float*)d_in[11];
  const float* Wu1 = (const float*)d_in[12];
  const float* bu1 = (const float*)d_in[13];
  const int*   ei  = (const int*)d_in[14];

  if (ws_size < F_END * sizeof(float)) return;

  float* W     = (float*)d_ws;
  float* A1    = W + F_A1;
  float* Zp    = W + F_SCR;   // aliased with Ac (disjoint live ranges)
  float* Ac    = W + F_SCR;
  float* A2    = W + F_A2;
  float* Ysc   = W + F_YSC;
  float* h0    = W + F_H0;
  float* h1    = W + F_H1;
  float* h2    = W + F_H2;
  float* u1    = W + F_U1;
  float* u1b   = W + F_U1B;
  float* Yfsc  = W + F_YF;
  float* score = W + F_SCORE;
  float* gate1 = W + F_GATE1;
  float* gate2 = W + F_GATE2;
  float* dis0  = W + F_DIS0;
  float* dis1  = W + F_DIS1;
  float* dis2  = W + F_DIS2;
  int* perm1   = (int*)(W + F_PERM1);
  int* perm2   = (int*)(W + F_PERM2);
  int* inv1    = (int*)(W + F_INV1);
  int* inv2    = (int*)(W + F_INV2);
  int* cnt_in  = (int*)(W + F_CNTI);
  int* cnt_out = (int*)(W + F_CNTO);
  int* selfc   = (int*)(W + F_SELF);
  int* col_in  = (int*)(W + F_CI);
  int* col_out = (int*)(W + F_CO);
  float* out   = (float*)d_out;

  // ---- init (single fused fill; ws re-poisoned to 0xAA before every timed launch) ----
  k_init<<<1024, 256, 0, stream>>>(A1, gate1, perm1, inv1, cnt_in, out + N0 * 3);

  // ---- edge lists + deg0 ----
  k_count<<<(E0 + 255) / 256, 256, 0, stream>>>(ei, cnt_in, cnt_out, selfc, col_in, col_out);
  k_dis0<<<(N0 + 255) / 256, 256, 0, stream>>>(cnt_in, selfc, dis0);

  // ---- level 0 GCN: h0 = tanh(gcn(A0, x, Wd0, bd0)) ----
  k_yw<<<N0, HID, 0, stream>>>(x, 32, N0, Wd0, nullptr, nullptr, dis0, Ysc);
  k_gcn_sparse<<<N0, HID, 0, stream>>>(Ysc, cnt_in, col_in, selfc, dis0, bd0, h0, 1);

  // ---- pool 1 ----
  k_score<<<N0, HID, 0, stream>>>(h0, p1, score);
  k_topk<<<1, 256, 0, stream>>>(score, N0, K1N, perm1, gate1, inv1);

  // ---- A1 = augment(A0)[perm1][:,perm1] (sparse pair enumeration) ----
  k_pairs<<<N0, 128, 0, stream>>>(cnt_in, col_in, cnt_out, col_out, inv1, A1);
  k_edge2<<<(E0 + 255) / 256, 256, 0, stream>>>(ei, inv1, A1);
  k_rowsum<<<K1N, 256, 0, stream>>>(A1, K1N, LD1, dis1);

  // ---- level 1 GCN: h1 = tanh(gcn(A1, h0[perm1]*gate1, Wd1, bd1)) ----
  k_yw<<<K1N, HID, 0, stream>>>(h0, HID, N0, Wd1, perm1, gate1, dis1, Ysc);
  k_zero_f32<<<8, 256, 0, stream>>>(Ysc + K1N * HID, (LD1 - K1N) * HID);  // K-pad rows
  k_gemm<<<dim3((K1N + BM - 1) / BM, KS), 256, 0, stream>>>(A1, K1N, LD1, Ysc, Zp, LD1 / KS);
  k_gcn_epi<<<(K1N * HID + 255) / 256, 256, 0, stream>>>(Zp, Ysc, dis1, bd1, h1, K1N, 1);

  // ---- pool 2 ----
  k_score<<<K1N, HID, 0, stream>>>(h1, p2, score);
  k_topk<<<1, 256, 0, stream>>>(score, K1N, K2N, perm2, gate2, inv2);

  // ---- A2 = augment(A1)[perm2][:,perm2] via column compaction + row-sparse AXPY ----
  k_cmp<<<K1N, 256, 0, stream>>>(A1, perm2, Ac);
  k_sq2<<<K2N, 256, 0, stream>>>(A1, Ac, perm2, A2);
  k_rowsum<<<K2N, 256, 0, stream>>>(A2, K2N, LD2, dis2);

  // ---- level 2 GCN: h2 = tanh(gcn(A2, h1[perm2]*gate2, Wd2, bd2)) ----
  k_yw<<<K2N, HID, 0, stream>>>(h1, HID, K1N, Wd2, perm2, gate2, dis2, Ysc);
  k_zero_f32<<<8, 256, 0, stream>>>(Ysc + K2N * HID, (LD2 - K2N) * HID);  // K-pad rows
  k_gemm<<<dim3((K2N + BM - 1) / BM, KS), 256, 0, stream>>>(A2, K2N, LD2, Ysc, Zp, LD2 / KS);
  k_gcn_epi<<<(K2N * HID + 255) / 256, 256, 0, stream>>>(Zp, Ysc, dis2, bd2, h2, K2N, 1);

  // ---- up path ----
  k_combine<<<(K1N * HID + 255) / 256, 256, 0, stream>>>(h1, h2, inv2, u1);
  k_yw<<<K1N, HID, 0, stream>>>(u1, HID, K1N, Wu0, nullptr, nullptr, dis1, Ysc);
  k_zero_f32<<<8, 256, 0, stream>>>(Ysc + K1N * HID, (LD1 - K1N) * HID);  // K-pad rows
  k_gemm<<<dim3((K1N + BM - 1) / BM, KS), 256, 0, stream>>>(A1, K1N, LD1, Ysc, Zp, LD1 / KS);
  k_gcn_epi<<<(K1N * HID + 255) / 256, 256, 0, stream>>>(Zp, Ysc, dis1, bu0, u1b, K1N, 1);

  // ---- final: drift = gcn(A0, h0 + scatter(u1b), Wu1, bu1); out = drift + 0.1*z ----
  k_yf<<<N0, HID, 0, stream>>>(h0, u1b, inv1, Wu1, dis0, Yfsc);
  k_final<<<(N0 * 3 + 255) / 256, 256, 0, stream>>>(Yfsc, cnt_in, col_in, selfc, dis0, bu1, z, out);
}

// Round 7
// 310.306 us; speedup vs baseline: 2.4463x; 1.2411x over previous
//
#include <hip/hip_runtime.h>
#include <hip/hip_bf16.h>

#define N0   3000
#define E0   48000
#define K1N  1500
#define K2N  750
#define HID  128
#define CAP  128
#define LD1  1536  // padded leading dim for A1 (= padded K for level-1 GEMMs)
#define LD2  768   // padded leading dim for A2/Ac (= padded K for level-2 GEMM)
#define BM   32    // GEMM rows per block
#define BK   64    // GEMM K-tile
#define KS   6     // GEMM K-split chunks (deterministic partials)
#define NPR  1504  // Zp row stride (= 47*32 >= padded row count of any GEMM)
#define ATS  36    // transposed A-tile stride (BM+4, bank-spread)

__device__ __forceinline__ unsigned fkey(float f) {
  unsigned u = __float_as_uint(f);
  return (u & 0x80000000u) ? ~u : (u | 0x80000000u);
}
__device__ __forceinline__ float inv_fkey(unsigned u) {
  unsigned v = (u & 0x80000000u) ? (u & 0x7FFFFFFFu) : ~u;
  return __uint_as_float(v);
}

// ---------------- workspace layout (float units) ----------------
constexpr size_t F_A1    = 0;                          // K1N*LD1
constexpr size_t F_SCR   = F_A1 + (size_t)K1N * LD1;   // max(Zp = KS*NPR*HID, Ac = K1N*LD2)
constexpr size_t SCR_SZ  = (size_t)KS * NPR * HID;     // 1,155,072 > 1,152,000
constexpr size_t F_A2    = F_SCR + SCR_SZ;             // K2N*LD2
constexpr size_t F_YSC   = F_A2 + (size_t)K2N * LD2;   // N0*HID (>= 1536 rows)
constexpr size_t F_H0    = F_YSC + (size_t)N0 * HID;   // N0*HID
constexpr size_t F_H1    = F_H0 + (size_t)N0 * HID;    // K1N*HID
constexpr size_t F_H2    = F_H1 + (size_t)K1N * HID;   // K2N*HID
constexpr size_t F_U1    = F_H2 + (size_t)K2N * HID;   // K1N*HID
constexpr size_t F_U1B   = F_U1 + (size_t)K1N * HID;   // K1N*HID
constexpr size_t F_YF    = F_U1B + (size_t)K1N * HID;  // N0*3
constexpr size_t F_SCORE = F_YF + (size_t)N0 * 3;      // N0
constexpr size_t F_GATE1 = F_SCORE + N0;               // K1N  } contiguous zero fill
constexpr size_t F_GATE2 = F_GATE1 + K1N;              // K2N  }
constexpr size_t F_DIS0  = F_GATE2 + K2N;              // N0
constexpr size_t F_DIS1  = F_DIS0 + N0;                // K1N
constexpr size_t F_DIS2  = F_DIS1 + K1N;               // K2N
constexpr size_t F_PERM1 = F_DIS2 + K2N;               // K1N (int) } contiguous 0 fill
constexpr size_t F_PERM2 = F_PERM1 + K1N;              // K2N (int) }
constexpr size_t F_INV1  = F_PERM2 + K2N;              // N0  (int) } contiguous -1 fill
constexpr size_t F_INV2  = F_INV1 + N0;                // K1N (int) }
constexpr size_t F_CNTI  = F_INV2 + K1N;               // N0  (int) } contiguous 0 fill
constexpr size_t F_CNTO  = F_CNTI + N0;                // N0  (int) }
constexpr size_t F_SELF  = F_CNTO + N0;                // N0  (int) }
constexpr size_t F_CI    = F_SELF + N0;                // N0*CAP (int)
constexpr size_t F_CO    = F_CI + (size_t)N0 * CAP;    // N0*CAP (int)
constexpr size_t F_END   = F_CO + (size_t)N0 * CAP;

// ---------------- init: all fills fused (1 dispatch) ----------------
__global__ void k_init(float* __restrict__ A1, float* __restrict__ gate,
                       int* __restrict__ perm, int* __restrict__ inv,
                       int* __restrict__ cnt, float* __restrict__ outlab) {
  int i = blockIdx.x * blockDim.x + threadIdx.x, st = gridDim.x * blockDim.x;
  for (int j = i; j < K1N * LD1; j += st) A1[j] = 0.0f;
  for (int j = i; j < K1N + K2N; j += st) gate[j] = 0.0f;
  for (int j = i; j < K1N + K2N; j += st) perm[j] = 0;
  for (int j = i; j < N0 + K1N; j += st) inv[j] = -1;
  for (int j = i; j < 3 * N0; j += st) cnt[j] = 0;
  for (int j = i; j < N0 * 29; j += st) outlab[j] = 0.0f;
}

// Build per-node edge lists: col_in[d] = srcs of non-self in-edges, col_out[s] = dsts.
__global__ void k_count(const int* __restrict__ ei, int* cnt_in, int* cnt_out, int* selfc,
                        int* col_in, int* col_out) {
  int e = blockIdx.x * blockDim.x + threadIdx.x;
  if (e >= E0) return;
  int s = ei[e], d = ei[E0 + e];
  if (s == d) { atomicAdd(&selfc[d], 1); return; }
  int a = atomicAdd(&cnt_in[d], 1);
  if (a < CAP) col_in[d * CAP + a] = s;
  int b = atomicAdd(&cnt_out[s], 1);
  if (b < CAP) col_out[s * CAP + b] = d;
}

__global__ void k_dis0(const int* cnt_in, const int* selfc, float* dis0) {
  int i = blockIdx.x * blockDim.x + threadIdx.x;
  if (i < N0) dis0[i] = 1.0f / sqrtf((float)(cnt_in[i] + selfc[i] + 2));
}

// Ysc[row][f] = (dis[row]*gate[row]) * sum_k X[src(row)][k] * Wm[k][f]
// LDS-tiled: 256 thr = 32 f-groups x 8 row-groups; BM=32 rows/block; 32-wide K tiles.
// Rows in [n, npad) are written as zeros (K-padding for the downstream GEMM).
// Accumulation order over k is ascending == previous k_yw (bit-identical).
__global__ __launch_bounds__(256) void k_yw2(const float* __restrict__ X, int Kin, int nsrc,
                                             int n, int npad,
                                             const float* __restrict__ Wm,
                                             const int* __restrict__ perm,
                                             const float* __restrict__ gate,
                                             const float* __restrict__ dis,
                                             float* __restrict__ Ysc) {
  __shared__ float Wt[32 * HID];   // 16 KB, [kk][f]
  __shared__ float Xt[32 * ATS];   // 4.6 KB, [kk][row] transposed
  int t = threadIdx.x;
  int r0 = blockIdx.x * BM;
  int f4 = (t & 31) * 4;
  int rg = t >> 5;                 // 0..7 -> rows r0 + rg*4 + {0..3}
  float4 acc0 = {0,0,0,0}, acc1 = {0,0,0,0}, acc2 = {0,0,0,0}, acc3 = {0,0,0,0};
  for (int kb = 0; kb < Kin; kb += 32) {
    // stage W tile: 32x128 floats = 1024 float4
    {
      const float4* src = (const float4*)(Wm + (size_t)kb * HID);
      float4* dst = (float4*)Wt;
#pragma unroll
      for (int i = 0; i < 4; ++i) dst[i * 256 + t] = src[i * 256 + t];
    }
    // stage X tile transposed: 32 rows x 32 k (row j = t>>3, k4 = (t&7)*4)
    {
      int j = t >> 3;
      int k4 = (t & 7) * 4;
      int r = r0 + j;
      int src_row = (r < n) ? r : (n - 1);
      if (perm) {
        int s = perm[src_row];
        if (s < 0) s = 0;
        if (s >= nsrc) s = nsrc - 1;
        src_row = s;
      }
      float4 xv = *(const float4*)(X + (size_t)src_row * Kin + kb + k4);
      Xt[(k4 + 0) * ATS + j] = xv.x;
      Xt[(k4 + 1) * ATS + j] = xv.y;
      Xt[(k4 + 2) * ATS + j] = xv.z;
      Xt[(k4 + 3) * ATS + j] = xv.w;
    }
    __syncthreads();
#pragma unroll 4
    for (int kk = 0; kk < 32; ++kk) {
      float4 y = *(const float4*)&Wt[kk * HID + f4];
      float4 a = *(const float4*)&Xt[kk * ATS + rg * 4];
      acc0.x += a.x * y.x; acc0.y += a.x * y.y; acc0.z += a.x * y.z; acc0.w += a.x * y.w;
      acc1.x += a.y * y.x; acc1.y += a.y * y.y; acc1.z += a.y * y.z; acc1.w += a.y * y.w;
      acc2.x += a.z * y.x; acc2.y += a.z * y.y; acc2.z += a.z * y.z; acc2.w += a.z * y.w;
      acc3.x += a.w * y.x; acc3.y += a.w * y.y; acc3.z += a.w * y.z; acc3.w += a.w * y.w;
    }
    __syncthreads();
  }
  int r = r0 + rg * 4;
  float4* accs[4] = {&acc0, &acc1, &acc2, &acc3};
#pragma unroll
  for (int j = 0; j < 4; ++j) {
    int row = r + j;
    if (row >= npad) continue;
    float4 v = {0, 0, 0, 0};
    if (row < n) {
      float g = gate ? gate[row] : 1.0f;
      float s = dis[row] * g;
      float4 a = *accs[j];
      v = make_float4(s * a.x, s * a.y, s * a.z, s * a.w);
    }
    *(float4*)&Ysc[(size_t)row * HID + f4] = v;
  }
}

// Level-0 sparse GCN aggregation: H[d] = act(dis0[d]*(sum_in Ysc[s] + (2+self)*Ysc[d]) + b)
__global__ void k_gcn_sparse(const float* __restrict__ Ysc, const int* __restrict__ cnt_in,
                             const int* __restrict__ col_in, const int* __restrict__ selfc,
                             const float* __restrict__ dis, const float* __restrict__ bias,
                             float* __restrict__ H, int act) {
  int d = blockIdx.x, f = threadIdx.x;
  int cnt = cnt_in[d]; if (cnt > CAP) cnt = CAP;
  float acc = (2.0f + (float)selfc[d]) * Ysc[d * HID + f];
  for (int e = 0; e < cnt; ++e) acc += Ysc[col_in[d * CAP + e] * HID + f];
  float z = dis[d] * acc + bias[f];
  H[d * HID + f] = act ? tanhf(z) : z;
}

// score[i] = tanh((H[i].p) / ||p||)   (p-norm recomputed per block, same order as before)
__global__ void k_score(const float* __restrict__ H, const float* __restrict__ p,
                        float* __restrict__ score) {
  __shared__ float red[HID];
  __shared__ float red2[HID];
  int i = blockIdx.x, t = threadIdx.x;
  float pv = p[t];
  red[t] = H[i * HID + t] * pv;
  red2[t] = pv * pv;
  __syncthreads();
  for (int s = 64; s > 0; s >>= 1) {
    if (t < s) { red[t] += red[t + s]; red2[t] += red2[t + s]; }
    __syncthreads();
  }
  if (t == 0) score[i] = tanhf(red[0] * (1.0f / sqrtf(red2[0])));
}

// Top-K, one 256-thread block. Keys staged in LDS; radix-select threshold with
// parallel suffix-scan; compaction by wave 0 via verified ballot scheme.
// Ties at threshold taken in lowest-index order (matches jax.lax.top_k).
__global__ __launch_bounds__(256) void k_topk(const float* __restrict__ score, int n, int K,
                                              int* __restrict__ perm, float* __restrict__ gatec,
                                              int* __restrict__ inv) {
  __shared__ unsigned keys[N0];      // n <= N0
  __shared__ int hist[256];
  __shared__ int sscan[257];
  __shared__ unsigned pfx_sh;
  __shared__ int rem_sh;
  int t = threadIdx.x;
  for (int i = t; i < n; i += 256) keys[i] = fkey(score[i]);
  __syncthreads();

  unsigned prefix = 0; int rem = K;
  for (int pass = 3; pass >= 0; --pass) {
    hist[t] = 0;
    __syncthreads();
    unsigned mhi = (pass == 3) ? 0u : (0xFFFFFFFFu << ((pass + 1) * 8));
    for (int i = t; i < n; i += 256) {
      unsigned u = keys[i];
      if ((u & mhi) == (prefix & mhi)) atomicAdd(&hist[(u >> (pass * 8)) & 255], 1);
    }
    __syncthreads();
    sscan[t] = hist[t];
    if (t == 0) sscan[256] = 0;
    __syncthreads();
    for (int off = 1; off < 256; off <<= 1) {
      int add = (t + off < 256) ? sscan[t + off] : 0;
      __syncthreads();
      sscan[t] += add;
      __syncthreads();
    }
    if (sscan[t] >= rem && sscan[t + 1] < rem) {
      pfx_sh = prefix | ((unsigned)t << (pass * 8));
      rem_sh = rem - sscan[t + 1];
    }
    __syncthreads();
    prefix = pfx_sh; rem = rem_sh;
    __syncthreads();
  }
  unsigned uthr = prefix;       // key of the K-th largest
  int c_gt = K - rem;           // count of keys strictly greater
  if (t >= 64) return;          // single-wave compaction (no further barriers)
  int lane = t;
  int base_gt = 0, base_eq = 0;
  for (int chunk = 0; chunk < n; chunk += 64) {
    int i = chunk + lane;
    bool valid = (i < n);
    unsigned u = valid ? keys[i] : 0u;
    bool isgt = valid && (u > uthr);
    bool iseq = valid && (u == uthr);
    unsigned long long mg = __ballot(isgt);
    unsigned long long me = __ballot(iseq);
    unsigned long long below = (lane == 0) ? 0ull : (~0ull >> (64 - lane));
    if (isgt) {
      int pos = base_gt + (int)__popcll(mg & below);
      perm[pos] = i; gatec[pos] = inv_fkey(u); inv[i] = pos;
    } else if (iseq) {
      int er = base_eq + (int)__popcll(me & below);
      if (er < rem) { int pos = c_gt + er; perm[pos] = i; gatec[pos] = inv_fkey(u); inv[i] = pos; }
    }
    base_gt += (int)__popcll(mg);
    base_eq += (int)__popcll(me);
  }
}

// A0 augment restricted to selected nodes: A1[inv[i],inv[j]] += 1 per 2-path i<-k<-j (i!=j)
__global__ void k_pairs(const int* __restrict__ cnt_in, const int* __restrict__ col_in,
                        const int* __restrict__ cnt_out, const int* __restrict__ col_out,
                        const int* __restrict__ inv, float* __restrict__ A1) {
  __shared__ int outl[CAP], inl[CAP], invo[CAP], invi[CAP];
  int k = blockIdx.x, t = threadIdx.x;
  int no = cnt_out[k]; if (no > CAP) no = CAP;
  int ni = cnt_in[k];  if (ni > CAP) ni = CAP;
  if (t < no) { int i = col_out[k * CAP + t]; outl[t] = i; invo[t] = inv[i]; }
  if (t < ni) { int j = col_in[k * CAP + t];  inl[t] = j;  invi[t] = inv[j]; }
  __syncthreads();
  for (int a = t; a < no; a += blockDim.x) {
    int i = outl[a], ii = invo[a];
    if (ii < 0) continue;
    for (int b = 0; b < ni; ++b) {
      int jj = invi[b];
      if (jj >= 0 && i != inl[b]) atomicAdd(&A1[(size_t)ii * LD1 + jj], 1.0f);
    }
  }
}

// + 2*A' restricted to selected nodes
__global__ void k_edge2(const int* __restrict__ ei, const int* __restrict__ inv,
                        float* __restrict__ A1) {
  int e = blockIdx.x * blockDim.x + threadIdx.x;
  if (e >= E0) return;
  int s = ei[e], d = ei[E0 + e];
  if (s == d) return;
  int a = inv[d], b = inv[s];
  if (a >= 0 && b >= 0) atomicAdd(&A1[(size_t)a * LD1 + b], 2.0f);
}

__global__ void k_rowsum(const float* __restrict__ A, int n, int ld, float* __restrict__ dis) {
  __shared__ float red[256];
  int r = blockIdx.x, t = threadIdx.x;
  float acc = 0.0f;
  for (int c = t; c < n; c += 256) acc += A[(size_t)r * ld + c];
  red[t] = acc; __syncthreads();
  for (int s = 128; s > 0; s >>= 1) { if (t < s) red[t] += red[t + s]; __syncthreads(); }
  if (t == 0) dis[r] = 1.0f / sqrtf(red[0] + 2.0f);
}

// Column compaction: Ac[k][b] = A1[k][perm2[b]]  (b < K2N, else 0); grid = K1N rows
__global__ __launch_bounds__(256) void k_cmp(const float* __restrict__ A1,
                                             const int* __restrict__ perm2,
                                             float* __restrict__ Ac) {
  __shared__ int q[K2N];
  int k = blockIdx.x, t = threadIdx.x;
  for (int i = t; i < K2N; i += 256) {
    int v = perm2[i];
    if (v < 0) v = 0;
    if (v >= K1N) v = K1N - 1;
    q[i] = v;
  }
  __syncthreads();
  const float* row = A1 + (size_t)k * LD1;
  float* dst = Ac + (size_t)k * LD2;
  for (int b = t; b < LD2; b += 256) dst[b] = (b < K2N) ? row[q[b]] : 0.0f;
}

// A2[a][b] = (b!=a) ? sum_k A1[qa][k]*Ac[k][b] + 2*A1[qa][perm2[b]] : 0
// Row-sparse AXPY over compacted columns; integer-exact fp32. Grid = K2N rows.
__global__ __launch_bounds__(256) void k_sq2(const float* __restrict__ A1,
                                             const float* __restrict__ Ac,
                                             const int* __restrict__ perm2,
                                             float* __restrict__ A2) {
  __shared__ int klist[K1N];
  __shared__ float wlist[K1N];
  __shared__ int nnz_sh;
  int a = blockIdx.x, t = threadIdx.x;
  int qa = perm2[a];
  if (qa < 0) qa = 0;
  if (qa >= K1N) qa = K1N - 1;
  if (t == 0) nnz_sh = 0;
  __syncthreads();
  const float* arow = A1 + (size_t)qa * LD1;
  for (int c = t; c < K1N; c += 256) {
    float w = arow[c];
    if (w != 0.0f) { int p = atomicAdd(&nnz_sh, 1); klist[p] = c; wlist[p] = w; }
  }
  __syncthreads();
  int nnz = nnz_sh;
  int c0 = t * 4;
  bool active = (c0 < LD2);
  float4 acc = make_float4(0.f, 0.f, 0.f, 0.f);
  int p = 0;
  for (; p + 4 <= nnz; p += 4) {   // 4 independent L2 loads in flight
    int k0 = klist[p], k1 = klist[p + 1], k2 = klist[p + 2], k3 = klist[p + 3];
    float w0 = wlist[p], w1 = wlist[p + 1], w2 = wlist[p + 2], w3 = wlist[p + 3];
    if (active) {
      float4 v0 = *(const float4*)&Ac[(size_t)k0 * LD2 + c0];
      float4 v1 = *(const float4*)&Ac[(size_t)k1 * LD2 + c0];
      float4 v2 = *(const float4*)&Ac[(size_t)k2 * LD2 + c0];
      float4 v3 = *(const float4*)&Ac[(size_t)k3 * LD2 + c0];
      acc.x += w0 * v0.x; acc.y += w0 * v0.y; acc.z += w0 * v0.z; acc.w += w0 * v0.w;
      acc.x += w1 * v1.x; acc.y += w1 * v1.y; acc.z += w1 * v1.z; acc.w += w1 * v1.w;
      acc.x += w2 * v2.x; acc.y += w2 * v2.y; acc.z += w2 * v2.z; acc.w += w2 * v2.w;
      acc.x += w3 * v3.x; acc.y += w3 * v3.y; acc.z += w3 * v3.z; acc.w += w3 * v3.w;
    }
  }
  for (; p < nnz; ++p) {
    int k = klist[p]; float w = wlist[p];
    if (active) {
      float4 v = *(const float4*)&Ac[(size_t)k * LD2 + c0];
      acc.x += w * v.x; acc.y += w * v.y; acc.z += w * v.z; acc.w += w * v.w;
    }
  }
  if (active) {
    float accv[4] = {acc.x, acc.y, acc.z, acc.w};
    float outv[4];
#pragma unroll
    for (int j = 0; j < 4; ++j) {
      int col = c0 + j;
      float v = 0.0f;
      if (col < K2N && col != a) {
        int qb = perm2[col];
        if (qb < 0) qb = 0;
        if (qb >= K1N) qb = K1N - 1;
        v = accv[j] + 2.0f * arow[qb];
      }
      outv[j] = v;
    }
    *(float4*)&A2[(size_t)a * LD2 + c0] = make_float4(outv[0], outv[1], outv[2], outv[3]);
  }
}

// LDS-tiled GEMM partial: Zp[s][r][f] = sum_{k in chunk s} A[r][k] * Y[k][f]
// block: 256 thr = 32 col-groups(f4) x 8 row-groups(4 rows); BM=32 rows, BK=64 K-tile.
// ld == padded K (zero-filled), kc = chunk width (multiple of BK).
__global__ __launch_bounds__(256) void k_gemm(const float* __restrict__ A, int n, int ld,
                                              const float* __restrict__ Y,
                                              float* __restrict__ Zp, int kc) {
  __shared__ float Yt[BK * HID];   // 32 KB, [kk][f]
  __shared__ float At[BK * ATS];   // 9 KB,  [kk][row] transposed
  int t = threadIdx.x;
  int r0 = blockIdx.x * BM;
  int k0 = blockIdx.y * kc;
  int f4 = (t & 31) * 4;
  int rg = t >> 5;                 // 0..7, rows r0 + rg*4 + {0..3}
  float4 acc0 = {0,0,0,0}, acc1 = {0,0,0,0}, acc2 = {0,0,0,0}, acc3 = {0,0,0,0};
  for (int kt = 0; kt < kc; kt += BK) {
    int kb = k0 + kt;
    {
      const float4* src = (const float4*)(Y + (size_t)kb * HID);
      float4* dst = (float4*)Yt;
#pragma unroll
      for (int i = 0; i < 8; ++i) dst[i * 256 + t] = src[i * 256 + t];
    }
#pragma unroll
    for (int ii = 0; ii < 2; ++ii) {
      int tix = t + ii * 256;
      int j = tix >> 4;                 // 0..31
      int kk4 = (tix & 15) * 4;         // 0..60
      int rr = r0 + j; if (rr >= n) rr = n - 1;
      float4 av = *(const float4*)(A + (size_t)rr * ld + kb + kk4);
      At[(kk4 + 0) * ATS + j] = av.x;
      At[(kk4 + 1) * ATS + j] = av.y;
      At[(kk4 + 2) * ATS + j] = av.z;
      At[(kk4 + 3) * ATS + j] = av.w;
    }
    __syncthreads();
#pragma unroll 4
    for (int kk = 0; kk < BK; ++kk) {
      float4 y = *(const float4*)&Yt[kk * HID + f4];
      float4 a = *(const float4*)&At[kk * ATS + rg * 4];
      acc0.x += a.x * y.x; acc0.y += a.x * y.y; acc0.z += a.x * y.z; acc0.w += a.x * y.w;
      acc1.x += a.y * y.x; acc1.y += a.y * y.y; acc1.z += a.y * y.z; acc1.w += a.y * y.w;
      acc2.x += a.z * y.x; acc2.y += a.z * y.y; acc2.z += a.z * y.z; acc2.w += a.z * y.w;
      acc3.x += a.w * y.x; acc3.y += a.w * y.y; acc3.z += a.w * y.z; acc3.w += a.w * y.w;
    }
    __syncthreads();
  }
  size_t zb = (size_t)blockIdx.y * NPR;
  int r = r0 + rg * 4;
  if (r + 0 < n) *(float4*)&Zp[(zb + r + 0) * HID + f4] = acc0;
  if (r + 1 < n) *(float4*)&Zp[(zb + r + 1) * HID + f4] = acc1;
  if (r + 2 < n) *(float4*)&Zp[(zb + r + 2) * HID + f4] = acc2;
  if (r + 3 < n) *(float4*)&Zp[(zb + r + 3) * HID + f4] = acc3;
}

// epilogue: Z[r][f] = act(dis[r]*(sum_s Zp[s][r][f] + 2*Ysc[r][f]) + bias[f])
__global__ void k_gcn_epi(const float* __restrict__ Zp, const float* __restrict__ Ysc,
                          const float* __restrict__ dis, const float* __restrict__ bias,
                          float* __restrict__ Z, int n, int act) {
  int idx = blockIdx.x * blockDim.x + threadIdx.x;
  if (idx >= n * HID) return;
  int r = idx >> 7, f = idx & 127;
  float acc = 0.0f;
#pragma unroll
  for (int s = 0; s < KS; ++s) acc += Zp[((size_t)s * NPR) * HID + idx];
  float z = dis[r] * (acc + 2.0f * Ysc[idx]) + bias[f];
  Z[idx] = act ? tanhf(z) : z;
}

__global__ void k_combine(const float* __restrict__ h1, const float* __restrict__ h2,
                          const int* __restrict__ inv2, float* __restrict__ u1) {
  int idx = blockIdx.x * blockDim.x + threadIdx.x;
  if (idx >= K1N * HID) return;
  int r = idx >> 7;
  float v = h1[idx];
  int ii = inv2[r];
  if (ii >= 0 && ii < K2N) v += h2[ii * HID + (idx & 127)];
  u1[idx] = v;
}

// Yfsc[i] = dis0[i] * ((h0[i] + scatter(u1b)) @ W_up1)   [N0 x 3]
__global__ void k_yf(const float* __restrict__ h0, const float* __restrict__ u1b,
                     const int* __restrict__ inv1, const float* __restrict__ Wup1,
                     const float* __restrict__ dis0, float* __restrict__ Yfsc) {
  __shared__ float red[3][HID];
  int i = blockIdx.x, t = threadIdx.x;
  float v = h0[i * HID + t];
  int ii = inv1[i];
  if (ii >= 0 && ii < K1N) v += u1b[ii * HID + t];
#pragma unroll
  for (int c = 0; c < 3; ++c) red[c][t] = v * Wup1[t * 3 + c];
  __syncthreads();
  for (int s = 64; s > 0; s >>= 1) {
    if (t < s) { red[0][t] += red[0][t + s]; red[1][t] += red[1][t + s]; red[2][t] += red[2][t + s]; }
    __syncthreads();
  }
  if (t < 3) Yfsc[i * 3 + t] = dis0[i] * red[t][0];
}

__global__ void k_final(const float* __restrict__ Yfsc, const int* __restrict__ cnt_in,
                        const int* __restrict__ col_in, const int* __restrict__ selfc,
                        const float* __restrict__ dis0, const float* __restrict__ bup1,
                        const float* __restrict__ z, float* __restrict__ out) {
  int idx = blockIdx.x * blockDim.x + threadIdx.x;
  if (idx >= N0 * 3) return;
  int d = idx / 3, c = idx - d * 3;
  int cnt = cnt_in[d]; if (cnt > CAP) cnt = CAP;
  float acc = (2.0f + (float)selfc[d]) * Yfsc[d * 3 + c];
  for (int e = 0; e < cnt; ++e) acc += Yfsc[col_in[d * CAP + e] * 3 + c];
  out[idx] = dis0[d] * acc + bup1[c] + 0.1f * z[idx];
}

extern "C" void kernel_launch(void* const* d_in, const int* in_sizes, int n_in,
                              void* d_out, int out_size, void* d_ws, size_t ws_size,
                              hipStream_t stream) {
  const float* x   = (const float*)d_in[0];
  const float* z   = (const float*)d_in[1];
  const float* Wd0 = (const float*)d_in[2];
  const float* bd0 = (const float*)d_in[3];
  const float* Wd1 = (const float*)d_in[4];
  const float* bd1 = (const float*)d_in[5];
  const float* Wd2 = (const float*)d_in[6];
  const float* bd2 = (const float*)d_in[7];
  const float* p1  = (const float*)d_in[8];
  const float* p2  = (const float*)d_in[9];
  const float* Wu0 = (const float*)d_in[10];
  const float* bu0 = (const float*)d_in[11];
  const float* Wu1 = (const float*)d_in[12];
  const float* bu1 = (const float*)d_in[13];
  const int*   ei  = (const int*)d_in[14];

  if (ws_size < F_END * sizeof(float)) return;

  float* W     = (float*)d_ws;
  float* A1    = W + F_A1;
  float* Zp    = W + F_SCR;   // aliased with Ac (disjoint live ranges)
  float* Ac    = W + F_SCR;
  float* A2    = W + F_A2;
  float* Ysc   = W + F_YSC;
  float* h0    = W + F_H0;
  float* h1    = W + F_H1;
  float* h2    = W + F_H2;
  float* u1    = W + F_U1;
  float* u1b   = W + F_U1B;
  float* Yfsc  = W + F_YF;
  float* score = W + F_SCORE;
  float* gate1 = W + F_GATE1;
  float* gate2 = W + F_GATE2;
  float* dis0  = W + F_DIS0;
  float* dis1  = W + F_DIS1;
  float* dis2  = W + F_DIS2;
  int* perm1   = (int*)(W + F_PERM1);
  int* perm2   = (int*)(W + F_PERM2);
  int* inv1    = (int*)(W + F_INV1);
  int* inv2    = (int*)(W + F_INV2);
  int* cnt_in  = (int*)(W + F_CNTI);
  int* cnt_out = (int*)(W + F_CNTO);
  int* selfc   = (int*)(W + F_SELF);
  int* col_in  = (int*)(W + F_CI);
  int* col_out = (int*)(W + F_CO);
  float* out   = (float*)d_out;

  // ---- init (single fused fill; ws re-poisoned to 0xAA before every timed launch) ----
  k_init<<<1024, 256, 0, stream>>>(A1, gate1, perm1, inv1, cnt_in, out + N0 * 3);

  // ---- edge lists + deg0 ----
  k_count<<<(E0 + 255) / 256, 256, 0, stream>>>(ei, cnt_in, cnt_out, selfc, col_in, col_out);
  k_dis0<<<(N0 + 255) / 256, 256, 0, stream>>>(cnt_in, selfc, dis0);

  // ---- level 0 GCN: h0 = tanh(gcn(A0, x, Wd0, bd0)) ----
  k_yw2<<<(N0 + BM - 1) / BM, 256, 0, stream>>>(x, 32, N0, N0, N0, Wd0, nullptr, nullptr, dis0, Ysc);
  k_gcn_sparse<<<N0, HID, 0, stream>>>(Ysc, cnt_in, col_in, selfc, dis0, bd0, h0, 1);

  // ---- pool 1 ----
  k_score<<<N0, HID, 0, stream>>>(h0, p1, score);
  k_topk<<<1, 256, 0, stream>>>(score, N0, K1N, perm1, gate1, inv1);

  // ---- A1 = augment(A0)[perm1][:,perm1] (sparse pair enumeration) ----
  k_pairs<<<N0, 128, 0, stream>>>(cnt_in, col_in, cnt_out, col_out, inv1, A1);
  k_edge2<<<(E0 + 255) / 256, 256, 0, stream>>>(ei, inv1, A1);
  k_rowsum<<<K1N, 256, 0, stream>>>(A1, K1N, LD1, dis1);

  // ---- level 1 GCN: h1 = tanh(gcn(A1, h0[perm1]*gate1, Wd1, bd1)) ----
  k_yw2<<<LD1 / BM, 256, 0, stream>>>(h0, HID, N0, K1N, LD1, Wd1, perm1, gate1, dis1, Ysc);
  k_gemm<<<dim3((K1N + BM - 1) / BM, KS), 256, 0, stream>>>(A1, K1N, LD1, Ysc, Zp, LD1 / KS);
  k_gcn_epi<<<(K1N * HID + 255) / 256, 256, 0, stream>>>(Zp, Ysc, dis1, bd1, h1, K1N, 1);

  // ---- pool 2 ----
  k_score<<<K1N, HID, 0, stream>>>(h1, p2, score);
  k_topk<<<1, 256, 0, stream>>>(score, K1N, K2N, perm2, gate2, inv2);

  // ---- A2 = augment(A1)[perm2][:,perm2] via column compaction + row-sparse AXPY ----
  k_cmp<<<K1N, 256, 0, stream>>>(A1, perm2, Ac);
  k_sq2<<<K2N, 256, 0, stream>>>(A1, Ac, perm2, A2);
  k_rowsum<<<K2N, 256, 0, stream>>>(A2, K2N, LD2, dis2);

  // ---- level 2 GCN: h2 = tanh(gcn(A2, h1[perm2]*gate2, Wd2, bd2)) ----
  k_yw2<<<LD2 / BM, 256, 0, stream>>>(h1, HID, K1N, K2N, LD2, Wd2, perm2, gate2, dis2, Ysc);
  k_gemm<<<dim3((K2N + BM - 1) / BM, KS), 256, 0, stream>>>(A2, K2N, LD2, Ysc, Zp, LD2 / KS);
  k_gcn_epi<<<(K2N * HID + 255) / 256, 256, 0, stream>>>(Zp, Ysc, dis2, bd2, h2, K2N, 1);

  // ---- up path ----
  k_combine<<<(K1N * HID + 255) / 256, 256, 0, stream>>>(h1, h2, inv2, u1);
  k_yw2<<<LD1 / BM, 256, 0, stream>>>(u1, HID, K1N, K1N, LD1, Wu0, nullptr, nullptr, dis1, Ysc);
  k_gemm<<<dim3((K1N + BM - 1) / BM, KS), 256, 0, stream>>>(A1, K1N, LD1, Ysc, Zp, LD1 / KS);
  k_gcn_epi<<<(K1N * HID + 255) / 256, 256, 0, stream>>>(Zp, Ysc, dis1, bu0, u1b, K1N, 1);

  // ---- final: drift = gcn(A0, h0 + scatter(u1b), Wu1, bu1); out = drift + 0.1*z ----
  k_yf<<<N0, HID, 0, stream>>>(h0, u1b, inv1, Wu1, dis0, Yfsc);
  k_final<<<(N0 * 3 + 255) / 256, 256, 0, stream>>>(Yfsc, cnt_in, col_in, selfc, dis0, bu1, z, out);
}

// Round 8
// 298.431 us; speedup vs baseline: 2.5437x; 1.0398x over previous
//
#include <hip/hip_runtime.h>
#include <hip/hip_bf16.h>

#define N0   3000
#define E0   48000
#define K1N  1500
#define K2N  750
#define HID  128
#define CAP  128
#define LD1  1536  // padded leading dim for A1
#define LD2  768   // padded leading dim for A2/Ac
#define BM   32    // row-tile for k_yw2
#define ATS  36    // transposed X-tile stride (BM+4, bank-spread)

__device__ __forceinline__ unsigned fkey(float f) {
  unsigned u = __float_as_uint(f);
  return (u & 0x80000000u) ? ~u : (u | 0x80000000u);
}
__device__ __forceinline__ float inv_fkey(unsigned u) {
  unsigned v = (u & 0x80000000u) ? (u & 0x7FFFFFFFu) : ~u;
  return __uint_as_float(v);
}

// ---------------- workspace layout (float units) ----------------
constexpr size_t F_A1    = 0;                          // K1N*LD1
constexpr size_t F_SCR   = F_A1 + (size_t)K1N * LD1;   // Ac = K1N*LD2
constexpr size_t SCR_SZ  = 1155072;                    // >= K1N*LD2 (1,152,000)
constexpr size_t F_A2    = F_SCR + SCR_SZ;             // K2N*LD2
constexpr size_t F_YSC   = F_A2 + (size_t)K2N * LD2;   // N0*HID
constexpr size_t F_H0    = F_YSC + (size_t)N0 * HID;   // N0*HID
constexpr size_t F_H1    = F_H0 + (size_t)N0 * HID;    // K1N*HID
constexpr size_t F_H2    = F_H1 + (size_t)K1N * HID;   // K2N*HID
constexpr size_t F_U1    = F_H2 + (size_t)K2N * HID;   // (unused, kept for layout)
constexpr size_t F_U1B   = F_U1 + (size_t)K1N * HID;   // K1N*HID
constexpr size_t F_YF    = F_U1B + (size_t)K1N * HID;  // N0*3
constexpr size_t F_SCORE = F_YF + (size_t)N0 * 3;      // N0
constexpr size_t F_GATE1 = F_SCORE + N0;               // K1N  } contiguous zero fill
constexpr size_t F_GATE2 = F_GATE1 + K1N;              // K2N  }
constexpr size_t F_DIS0  = F_GATE2 + K2N;              // (unused)
constexpr size_t F_DIS1  = F_DIS0 + N0;                // K1N
constexpr size_t F_DIS2  = F_DIS1 + K1N;               // K2N
constexpr size_t F_PERM1 = F_DIS2 + K2N;               // K1N (int) } contiguous 0 fill
constexpr size_t F_PERM2 = F_PERM1 + K1N;              // K2N (int) }
constexpr size_t F_INV1  = F_PERM2 + K2N;              // N0  (int) } contiguous -1 fill
constexpr size_t F_INV2  = F_INV1 + N0;                // K1N (int) }
constexpr size_t F_CNTI  = F_INV2 + K1N;               // N0  (int) } contiguous 0 fill
constexpr size_t F_CNTO  = F_CNTI + N0;                // N0  (int) }
constexpr size_t F_SELF  = F_CNTO + N0;                // N0  (int) }
constexpr size_t F_CI    = F_SELF + N0;                // N0*CAP (int)
constexpr size_t F_CO    = F_CI + (size_t)N0 * CAP;    // N0*CAP (int)
constexpr size_t F_END   = F_CO + (size_t)N0 * CAP;

// ---------------- init: all fills fused (1 dispatch) ----------------
__global__ void k_init(float* __restrict__ A1, float* __restrict__ gate,
                       int* __restrict__ perm, int* __restrict__ inv,
                       int* __restrict__ cnt, float* __restrict__ outlab) {
  int i = blockIdx.x * blockDim.x + threadIdx.x, st = gridDim.x * blockDim.x;
  for (int j = i; j < K1N * LD1; j += st) A1[j] = 0.0f;
  for (int j = i; j < K1N + K2N; j += st) gate[j] = 0.0f;
  for (int j = i; j < K1N + K2N; j += st) perm[j] = 0;
  for (int j = i; j < N0 + K1N; j += st) inv[j] = -1;
  for (int j = i; j < 3 * N0; j += st) cnt[j] = 0;
  for (int j = i; j < N0 * 29; j += st) outlab[j] = 0.0f;
}

// Build per-node edge lists: col_in[d] = srcs of non-self in-edges, col_out[s] = dsts.
__global__ void k_count(const int* __restrict__ ei, int* cnt_in, int* cnt_out, int* selfc,
                        int* col_in, int* col_out) {
  int e = blockIdx.x * blockDim.x + threadIdx.x;
  if (e >= E0) return;
  int s = ei[e], d = ei[E0 + e];
  if (s == d) { atomicAdd(&selfc[d], 1); return; }
  int a = atomicAdd(&cnt_in[d], 1);
  if (a < CAP) col_in[d * CAP + a] = s;
  int b = atomicAdd(&cnt_out[s], 1);
  if (b < CAP) col_out[s * CAP + b] = d;
}

// Ysc[row][f] = scale(row) * sum_k Xeff[src(row)][k] * Wm[k][f]
// Xeff = X (+ X2[inv2c[row]] if combine). scale = (dis ? dis : 1/sqrt(cnt+self+2)) * gate.
// LDS-tiled: 256 thr; BM=32 rows/block; 32-wide K tiles; ascending-k accumulation.
__global__ __launch_bounds__(256) void k_yw2(const float* __restrict__ X,
                                             const float* __restrict__ X2,
                                             const int* __restrict__ inv2c,
                                             int Kin, int nsrc, int n,
                                             const float* __restrict__ Wm,
                                             const int* __restrict__ perm,
                                             const float* __restrict__ gate,
                                             const float* __restrict__ dis,
                                             const int* __restrict__ cntd,
                                             const int* __restrict__ selfd,
                                             float* __restrict__ Ysc) {
  __shared__ float Wt[32 * HID];   // 16 KB, [kk][f]
  __shared__ float Xt[32 * ATS];   // 4.6 KB, [kk][row] transposed
  int t = threadIdx.x;
  int r0 = blockIdx.x * BM;
  int f4 = (t & 31) * 4;
  int rg = t >> 5;                 // 0..7 -> rows r0 + rg*4 + {0..3}
  float4 acc0 = {0,0,0,0}, acc1 = {0,0,0,0}, acc2 = {0,0,0,0}, acc3 = {0,0,0,0};
  for (int kb = 0; kb < Kin; kb += 32) {
    {
      const float4* src = (const float4*)(Wm + (size_t)kb * HID);
      float4* dst = (float4*)Wt;
#pragma unroll
      for (int i = 0; i < 4; ++i) dst[i * 256 + t] = src[i * 256 + t];
    }
    {
      int j = t >> 3;
      int k4 = (t & 7) * 4;
      int r = r0 + j;
      int src_row = (r < n) ? r : (n - 1);
      if (perm) {
        int s = perm[src_row];
        if (s < 0) s = 0;
        if (s >= nsrc) s = nsrc - 1;
        src_row = s;
      }
      float4 xv = *(const float4*)(X + (size_t)src_row * Kin + kb + k4);
      if (X2) {
        int ii = inv2c[src_row];
        if (ii >= 0 && ii < K2N) {
          float4 x2 = *(const float4*)(X2 + (size_t)ii * Kin + kb + k4);
          xv.x += x2.x; xv.y += x2.y; xv.z += x2.z; xv.w += x2.w;
        }
      }
      Xt[(k4 + 0) * ATS + j] = xv.x;
      Xt[(k4 + 1) * ATS + j] = xv.y;
      Xt[(k4 + 2) * ATS + j] = xv.z;
      Xt[(k4 + 3) * ATS + j] = xv.w;
    }
    __syncthreads();
#pragma unroll 4
    for (int kk = 0; kk < 32; ++kk) {
      float4 y = *(const float4*)&Wt[kk * HID + f4];
      float4 a = *(const float4*)&Xt[kk * ATS + rg * 4];
      acc0.x += a.x * y.x; acc0.y += a.x * y.y; acc0.z += a.x * y.z; acc0.w += a.x * y.w;
      acc1.x += a.y * y.x; acc1.y += a.y * y.y; acc1.z += a.y * y.z; acc1.w += a.y * y.w;
      acc2.x += a.z * y.x; acc2.y += a.z * y.y; acc2.z += a.z * y.z; acc2.w += a.z * y.w;
      acc3.x += a.w * y.x; acc3.y += a.w * y.y; acc3.z += a.w * y.z; acc3.w += a.w * y.w;
    }
    __syncthreads();
  }
  int r = r0 + rg * 4;
  float4* accs[4] = {&acc0, &acc1, &acc2, &acc3};
#pragma unroll
  for (int j = 0; j < 4; ++j) {
    int row = r + j;
    if (row >= n) continue;
    float g = gate ? gate[row] : 1.0f;
    float d = dis ? dis[row] : (1.0f / sqrtf((float)(cntd[row] + selfd[row] + 2)));
    float s = d * g;
    float4 a = *accs[j];
    *(float4*)&Ysc[(size_t)row * HID + f4] = make_float4(s * a.x, s * a.y, s * a.z, s * a.w);
  }
}

// Level-0 sparse GCN + fused score:
// H[d] = tanh(dis0[d]*(sum_in Ysc[s] + (2+self)*Ysc[d]) + b); score[d] = tanh(H[d].p/||p||)
__global__ void k_gcn_sparse(const float* __restrict__ Ysc, const int* __restrict__ cnt_in,
                             const int* __restrict__ col_in, const int* __restrict__ selfc,
                             const float* __restrict__ bias, const float* __restrict__ p,
                             float* __restrict__ H, float* __restrict__ score) {
  __shared__ float red[HID];
  __shared__ float red2[HID];
  int d = blockIdx.x, f = threadIdx.x;
  int cntu = cnt_in[d];
  int cnt = cntu > CAP ? CAP : cntu;
  float acc = (2.0f + (float)selfc[d]) * Ysc[d * HID + f];
  for (int e = 0; e < cnt; ++e) acc += Ysc[col_in[d * CAP + e] * HID + f];
  float d0 = 1.0f / sqrtf((float)(cntu + selfc[d] + 2));
  float h = tanhf(d0 * acc + bias[f]);
  H[d * HID + f] = h;
  float pv = p[f];
  red[f] = h * pv;
  red2[f] = pv * pv;
  __syncthreads();
  for (int s = 64; s > 0; s >>= 1) {
    if (f < s) { red[f] += red[f + s]; red2[f] += red2[f + s]; }
    __syncthreads();
  }
  if (f == 0) score[d] = tanhf(red[0] * (1.0f / sqrtf(red2[0])));
}

// Top-K, one 256-thread block. Keys staged in LDS; radix-select threshold with
// parallel suffix-scan; compaction by wave 0 via verified ballot scheme.
__global__ __launch_bounds__(256) void k_topk(const float* __restrict__ score, int n, int K,
                                              int* __restrict__ perm, float* __restrict__ gatec,
                                              int* __restrict__ inv) {
  __shared__ unsigned keys[N0];      // n <= N0
  __shared__ int hist[256];
  __shared__ int sscan[257];
  __shared__ unsigned pfx_sh;
  __shared__ int rem_sh;
  int t = threadIdx.x;
  for (int i = t; i < n; i += 256) keys[i] = fkey(score[i]);
  __syncthreads();

  unsigned prefix = 0; int rem = K;
  for (int pass = 3; pass >= 0; --pass) {
    hist[t] = 0;
    __syncthreads();
    unsigned mhi = (pass == 3) ? 0u : (0xFFFFFFFFu << ((pass + 1) * 8));
    for (int i = t; i < n; i += 256) {
      unsigned u = keys[i];
      if ((u & mhi) == (prefix & mhi)) atomicAdd(&hist[(u >> (pass * 8)) & 255], 1);
    }
    __syncthreads();
    sscan[t] = hist[t];
    if (t == 0) sscan[256] = 0;
    __syncthreads();
    for (int off = 1; off < 256; off <<= 1) {
      int add = (t + off < 256) ? sscan[t + off] : 0;
      __syncthreads();
      sscan[t] += add;
      __syncthreads();
    }
    if (sscan[t] >= rem && sscan[t + 1] < rem) {
      pfx_sh = prefix | ((unsigned)t << (pass * 8));
      rem_sh = rem - sscan[t + 1];
    }
    __syncthreads();
    prefix = pfx_sh; rem = rem_sh;
    __syncthreads();
  }
  unsigned uthr = prefix;
  int c_gt = K - rem;
  if (t >= 64) return;
  int lane = t;
  int base_gt = 0, base_eq = 0;
  for (int chunk = 0; chunk < n; chunk += 64) {
    int i = chunk + lane;
    bool valid = (i < n);
    unsigned u = valid ? keys[i] : 0u;
    bool isgt = valid && (u > uthr);
    bool iseq = valid && (u == uthr);
    unsigned long long mg = __ballot(isgt);
    unsigned long long me = __ballot(iseq);
    unsigned long long below = (lane == 0) ? 0ull : (~0ull >> (64 - lane));
    if (isgt) {
      int pos = base_gt + (int)__popcll(mg & below);
      perm[pos] = i; gatec[pos] = inv_fkey(u); inv[i] = pos;
    } else if (iseq) {
      int er = base_eq + (int)__popcll(me & below);
      if (er < rem) { int pos = c_gt + er; perm[pos] = i; gatec[pos] = inv_fkey(u); inv[i] = pos; }
    }
    base_gt += (int)__popcll(mg);
    base_eq += (int)__popcll(me);
  }
}

// A0 augment restricted to selected nodes, fused with the +2*A' term:
// per 2-path i<-k<-j (i!=j): A1[inv[i],inv[j]] += 1;  per in-edge j->k: A1[inv[k],inv[j]] += 2
__global__ void k_pairs(const int* __restrict__ cnt_in, const int* __restrict__ col_in,
                        const int* __restrict__ cnt_out, const int* __restrict__ col_out,
                        const int* __restrict__ inv, float* __restrict__ A1) {
  __shared__ int outl[CAP], inl[CAP], invo[CAP], invi[CAP];
  int k = blockIdx.x, t = threadIdx.x;
  int no = cnt_out[k]; if (no > CAP) no = CAP;
  int ni = cnt_in[k];  if (ni > CAP) ni = CAP;
  if (t < no) { int i = col_out[k * CAP + t]; outl[t] = i; invo[t] = inv[i]; }
  if (t < ni) { int j = col_in[k * CAP + t];  inl[t] = j;  invi[t] = inv[j]; }
  __syncthreads();
  int invk = inv[k];
  if (t < ni && invk >= 0) {
    int jj = invi[t];
    if (jj >= 0) atomicAdd(&A1[(size_t)invk * LD1 + jj], 2.0f);   // edge term (2*A')
  }
  for (int a = t; a < no; a += blockDim.x) {
    int i = outl[a], ii = invo[a];
    if (ii < 0) continue;
    for (int b = 0; b < ni; ++b) {
      int jj = invi[b];
      if (jj >= 0 && i != inl[b]) atomicAdd(&A1[(size_t)ii * LD1 + jj], 1.0f);
    }
  }
}

__global__ void k_rowsum(const float* __restrict__ A, int n, int ld, float* __restrict__ dis) {
  __shared__ float red[256];
  int r = blockIdx.x, t = threadIdx.x;
  float acc = 0.0f;
  for (int c = t; c < n; c += 256) acc += A[(size_t)r * ld + c];
  red[t] = acc; __syncthreads();
  for (int s = 128; s > 0; s >>= 1) { if (t < s) red[t] += red[t + s]; __syncthreads(); }
  if (t == 0) dis[r] = 1.0f / sqrtf(red[0] + 2.0f);
}

// Column compaction: Ac[k][b] = A1[k][perm2[b]]  (b < K2N, else 0); grid = K1N rows
__global__ __launch_bounds__(256) void k_cmp(const float* __restrict__ A1,
                                             const int* __restrict__ perm2,
                                             float* __restrict__ Ac) {
  __shared__ int q[K2N];
  int k = blockIdx.x, t = threadIdx.x;
  for (int i = t; i < K2N; i += 256) {
    int v = perm2[i];
    if (v < 0) v = 0;
    if (v >= K1N) v = K1N - 1;
    q[i] = v;
  }
  __syncthreads();
  const float* row = A1 + (size_t)k * LD1;
  float* dst = Ac + (size_t)k * LD2;
  for (int b = t; b < LD2; b += 256) dst[b] = (b < K2N) ? row[q[b]] : 0.0f;
}

// A2[a][b] = (b!=a) ? sum_k A1[qa][k]*Ac[k][b] + 2*A1[qa][perm2[b]] : 0
// Row-sparse AXPY over compacted columns; integer-exact fp32. Grid = K2N rows.
__global__ __launch_bounds__(256) void k_sq2(const float* __restrict__ A1,
                                             const float* __restrict__ Ac,
                                             const int* __restrict__ perm2,
                                             float* __restrict__ A2) {
  __shared__ int klist[K1N];
  __shared__ float wlist[K1N];
  __shared__ int nnz_sh;
  int a = blockIdx.x, t = threadIdx.x;
  int qa = perm2[a];
  if (qa < 0) qa = 0;
  if (qa >= K1N) qa = K1N - 1;
  if (t == 0) nnz_sh = 0;
  __syncthreads();
  const float* arow = A1 + (size_t)qa * LD1;
  for (int c = t; c < K1N; c += 256) {
    float w = arow[c];
    if (w != 0.0f) { int p = atomicAdd(&nnz_sh, 1); klist[p] = c; wlist[p] = w; }
  }
  __syncthreads();
  int nnz = nnz_sh;
  int c0 = t * 4;
  bool active = (c0 < LD2);
  float4 acc = make_float4(0.f, 0.f, 0.f, 0.f);
  int p = 0;
  for (; p + 4 <= nnz; p += 4) {
    int k0 = klist[p], k1 = klist[p + 1], k2 = klist[p + 2], k3 = klist[p + 3];
    float w0 = wlist[p], w1 = wlist[p + 1], w2 = wlist[p + 2], w3 = wlist[p + 3];
    if (active) {
      float4 v0 = *(const float4*)&Ac[(size_t)k0 * LD2 + c0];
      float4 v1 = *(const float4*)&Ac[(size_t)k1 * LD2 + c0];
      float4 v2 = *(const float4*)&Ac[(size_t)k2 * LD2 + c0];
      float4 v3 = *(const float4*)&Ac[(size_t)k3 * LD2 + c0];
      acc.x += w0 * v0.x; acc.y += w0 * v0.y; acc.z += w0 * v0.z; acc.w += w0 * v0.w;
      acc.x += w1 * v1.x; acc.y += w1 * v1.y; acc.z += w1 * v1.z; acc.w += w1 * v1.w;
      acc.x += w2 * v2.x; acc.y += w2 * v2.y; acc.z += w2 * v2.z; acc.w += w2 * v2.w;
      acc.x += w3 * v3.x; acc.y += w3 * v3.y; acc.z += w3 * v3.z; acc.w += w3 * v3.w;
    }
  }
  for (; p < nnz; ++p) {
    int k = klist[p]; float w = wlist[p];
    if (active) {
      float4 v = *(const float4*)&Ac[(size_t)k * LD2 + c0];
      acc.x += w * v.x; acc.y += w * v.y; acc.z += w * v.z; acc.w += w * v.w;
    }
  }
  if (active) {
    float accv[4] = {acc.x, acc.y, acc.z, acc.w};
    float outv[4];
#pragma unroll
    for (int j = 0; j < 4; ++j) {
      int col = c0 + j;
      float v = 0.0f;
      if (col < K2N && col != a) {
        int qb = perm2[col];
        if (qb < 0) qb = 0;
        if (qb >= K1N) qb = K1N - 1;
        v = accv[j] + 2.0f * arow[qb];
      }
      outv[j] = v;
    }
    *(float4*)&A2[(size_t)a * LD2 + c0] = make_float4(outv[0], outv[1], outv[2], outv[3]);
  }
}

// Row-sparse GCN aggregation + epilogue (+ optional fused score):
// H[r][f] = act(dis[r]*(sum_{k: A[r][k]!=0} A[r][k]*Ysc[k][f] + 2*Ysc[r][f]) + bias[f])
// klist built in ascending-k order (deterministic) via per-chunk ballot compaction.
__global__ __launch_bounds__(128) void k_spmv(const float* __restrict__ A, int ncols, int ld,
                                              const float* __restrict__ Ysc,
                                              const float* __restrict__ dis,
                                              const float* __restrict__ bias,
                                              const float* __restrict__ p,
                                              float* __restrict__ H,
                                              float* __restrict__ score, int act) {
  __shared__ int klist[K1N];
  __shared__ float wlist[K1N];
  __shared__ int cntw[2];
  __shared__ float red[HID];
  __shared__ float red2[HID];
  int r = blockIdx.x, t = threadIdx.x;
  const float* arow = A + (size_t)r * ld;
  int wid = t >> 6, lane = t & 63;
  unsigned long long below = (lane == 0) ? 0ull : (~0ull >> (64 - lane));
  int base = 0;
  for (int c0 = 0; c0 < ncols; c0 += 128) {
    int col = c0 + t;
    float w = (col < ncols) ? arow[col] : 0.0f;
    bool nz = (w != 0.0f);
    unsigned long long m = __ballot(nz);
    if (lane == 0) cntw[wid] = (int)__popcll(m);
    __syncthreads();
    int pos = base + (wid ? cntw[0] : 0) + (int)__popcll(m & below);
    if (nz) { klist[pos] = col; wlist[pos] = w; }
    base += cntw[0] + cntw[1];
    __syncthreads();
  }
  int nnz = base;
  float acc = 0.0f;
  int pp = 0;
  for (; pp + 4 <= nnz; pp += 4) {
    float y0 = Ysc[(size_t)klist[pp + 0] * HID + t];
    float y1 = Ysc[(size_t)klist[pp + 1] * HID + t];
    float y2 = Ysc[(size_t)klist[pp + 2] * HID + t];
    float y3 = Ysc[(size_t)klist[pp + 3] * HID + t];
    acc += wlist[pp + 0] * y0;
    acc += wlist[pp + 1] * y1;
    acc += wlist[pp + 2] * y2;
    acc += wlist[pp + 3] * y3;
  }
  for (; pp < nnz; ++pp) acc += wlist[pp] * Ysc[(size_t)klist[pp] * HID + t];
  float zv = dis[r] * (acc + 2.0f * Ysc[(size_t)r * HID + t]) + bias[t];
  float h = act ? tanhf(zv) : zv;
  H[(size_t)r * HID + t] = h;
  if (p) {
    float pv = p[t];
    red[t] = h * pv;
    red2[t] = pv * pv;
    __syncthreads();
    for (int s = 64; s > 0; s >>= 1) {
      if (t < s) { red[t] += red[t + s]; red2[t] += red2[t + s]; }
      __syncthreads();
    }
    if (t == 0) score[r] = tanhf(red[0] * (1.0f / sqrtf(red2[0])));
  }
}

// Yfsc[i] = dis0[i] * ((h0[i] + scatter(u1b)) @ W_up1)   [N0 x 3]
__global__ void k_yf(const float* __restrict__ h0, const float* __restrict__ u1b,
                     const int* __restrict__ inv1, const float* __restrict__ Wup1,
                     const int* __restrict__ cnt_in, const int* __restrict__ selfc,
                     float* __restrict__ Yfsc) {
  __shared__ float red[3][HID];
  int i = blockIdx.x, t = threadIdx.x;
  float v = h0[i * HID + t];
  int ii = inv1[i];
  if (ii >= 0 && ii < K1N) v += u1b[ii * HID + t];
#pragma unroll
  for (int c = 0; c < 3; ++c) red[c][t] = v * Wup1[t * 3 + c];
  __syncthreads();
  for (int s = 64; s > 0; s >>= 1) {
    if (t < s) { red[0][t] += red[0][t + s]; red[1][t] += red[1][t + s]; red[2][t] += red[2][t + s]; }
    __syncthreads();
  }
  if (t < 3) {
    float d0 = 1.0f / sqrtf((float)(cnt_in[i] + selfc[i] + 2));
    Yfsc[i * 3 + t] = d0 * red[t][0];
  }
}

__global__ void k_final(const float* __restrict__ Yfsc, const int* __restrict__ cnt_in,
                        const int* __restrict__ col_in, const int* __restrict__ selfc,
                        const float* __restrict__ bup1, const float* __restrict__ z,
                        float* __restrict__ out) {
  int idx = blockIdx.x * blockDim.x + threadIdx.x;
  if (idx >= N0 * 3) return;
  int d = idx / 3, c = idx - d * 3;
  int cntu = cnt_in[d];
  int cnt = cntu > CAP ? CAP : cntu;
  float acc = (2.0f + (float)selfc[d]) * Yfsc[d * 3 + c];
  for (int e = 0; e < cnt; ++e) acc += Yfsc[col_in[d * CAP + e] * 3 + c];
  float d0 = 1.0f / sqrtf((float)(cntu + selfc[d] + 2));
  out[idx] = d0 * acc + bup1[c] + 0.1f * z[idx];
}

extern "C" void kernel_launch(void* const* d_in, const int* in_sizes, int n_in,
                              void* d_out, int out_size, void* d_ws, size_t ws_size,
                              hipStream_t stream) {
  const float* x   = (const float*)d_in[0];
  const float* z   = (const float*)d_in[1];
  const float* Wd0 = (const float*)d_in[2];
  const float* bd0 = (const float*)d_in[3];
  const float* Wd1 = (const float*)d_in[4];
  const float* bd1 = (const float*)d_in[5];
  const float* Wd2 = (const float*)d_in[6];
  const float* bd2 = (const float*)d_in[7];
  const float* p1  = (const float*)d_in[8];
  const float* p2  = (const float*)d_in[9];
  const float* Wu0 = (const float*)d_in[10];
  const float* bu0 = (const float*)d_in[11];
  const float* Wu1 = (const float*)d_in[12];
  const float* bu1 = (const float*)d_in[13];
  const int*   ei  = (const int*)d_in[14];

  if (ws_size < F_END * sizeof(float)) return;

  float* W     = (float*)d_ws;
  float* A1    = W + F_A1;
  float* Ac    = W + F_SCR;
  float* A2    = W + F_A2;
  float* Ysc   = W + F_YSC;
  float* h0    = W + F_H0;
  float* h1    = W + F_H1;
  float* h2    = W + F_H2;
  float* u1b   = W + F_U1B;
  float* Yfsc  = W + F_YF;
  float* score = W + F_SCORE;
  float* gate1 = W + F_GATE1;
  float* gate2 = W + F_GATE2;
  float* dis1  = W + F_DIS1;
  float* dis2  = W + F_DIS2;
  int* perm1   = (int*)(W + F_PERM1);
  int* perm2   = (int*)(W + F_PERM2);
  int* inv1    = (int*)(W + F_INV1);
  int* inv2    = (int*)(W + F_INV2);
  int* cnt_in  = (int*)(W + F_CNTI);
  int* cnt_out = (int*)(W + F_CNTO);
  int* selfc   = (int*)(W + F_SELF);
  int* col_in  = (int*)(W + F_CI);
  int* col_out = (int*)(W + F_CO);
  float* out   = (float*)d_out;

  // ---- init (single fused fill) ----
  k_init<<<1024, 256, 0, stream>>>(A1, gate1, perm1, inv1, cnt_in, out + N0 * 3);

  // ---- edge lists ----
  k_count<<<(E0 + 255) / 256, 256, 0, stream>>>(ei, cnt_in, cnt_out, selfc, col_in, col_out);

  // ---- level 0 GCN + pool-1 score (dis0 inline) ----
  k_yw2<<<(N0 + BM - 1) / BM, 256, 0, stream>>>(x, nullptr, nullptr, 32, N0, N0, Wd0,
                                                nullptr, nullptr, nullptr, cnt_in, selfc, Ysc);
  k_gcn_sparse<<<N0, HID, 0, stream>>>(Ysc, cnt_in, col_in, selfc, bd0, p1, h0, score);
  k_topk<<<1, 256, 0, stream>>>(score, N0, K1N, perm1, gate1, inv1);

  // ---- A1 = augment(A0)[perm1][:,perm1] (pairs + edge term fused) ----
  k_pairs<<<N0, 128, 0, stream>>>(cnt_in, col_in, cnt_out, col_out, inv1, A1);
  k_rowsum<<<K1N, 256, 0, stream>>>(A1, K1N, LD1, dis1);

  // ---- level 1 GCN (sparse) + pool-2 score fused ----
  k_yw2<<<(K1N + BM - 1) / BM, 256, 0, stream>>>(h0, nullptr, nullptr, HID, N0, K1N, Wd1,
                                                 perm1, gate1, dis1, nullptr, nullptr, Ysc);
  k_spmv<<<K1N, 128, 0, stream>>>(A1, K1N, LD1, Ysc, dis1, bd1, p2, h1, score, 1);
  k_topk<<<1, 256, 0, stream>>>(score, K1N, K2N, perm2, gate2, inv2);

  // ---- A2 = augment(A1)[perm2][:,perm2] via column compaction + row-sparse AXPY ----
  k_cmp<<<K1N, 256, 0, stream>>>(A1, perm2, Ac);
  k_sq2<<<K2N, 256, 0, stream>>>(A1, Ac, perm2, A2);
  k_rowsum<<<K2N, 256, 0, stream>>>(A2, K2N, LD2, dis2);

  // ---- level 2 GCN (sparse) ----
  k_yw2<<<(K2N + BM - 1) / BM, 256, 0, stream>>>(h1, nullptr, nullptr, HID, K1N, K2N, Wd2,
                                                 perm2, gate2, dis2, nullptr, nullptr, Ysc);
  k_spmv<<<K2N, 128, 0, stream>>>(A2, K2N, LD2, Ysc, dis2, bd2, nullptr, h2, nullptr, 1);

  // ---- up path (combine fused into staging) ----
  k_yw2<<<(K1N + BM - 1) / BM, 256, 0, stream>>>(h1, h2, inv2, HID, K1N, K1N, Wu0,
                                                 nullptr, nullptr, dis1, nullptr, nullptr, Ysc);
  k_spmv<<<K1N, 128, 0, stream>>>(A1, K1N, LD1, Ysc, dis1, bu0, nullptr, u1b, nullptr, 1);

  // ---- final: drift = gcn(A0, h0 + scatter(u1b), Wu1, bu1); out = drift + 0.1*z ----
  k_yf<<<N0, HID, 0, stream>>>(h0, u1b, inv1, Wu1, cnt_in, selfc, Yfsc);
  k_final<<<(N0 * 3 + 255) / 256, 256, 0, stream>>>(Yfsc, cnt_in, col_in, selfc, bu1, z, out);
}